// Round 4
// baseline (4326.757 us; speedup 1.0000x reference)
//
#include <hip/hip_runtime.h>
#include <stdint.h>

typedef unsigned short u16;
typedef unsigned char u8;
typedef unsigned int u32;
typedef __attribute__((ext_vector_type(8))) short short8;
typedef __attribute__((ext_vector_type(4))) float f32x4;

#define NSTEP 26
#define NB 512
#define NT 128
#define NH 256
#define NCLS 100

#define SP 32.0f     // proj_H int8 scale
#define SH 24.0f     // batch_H int8 scale
#define SW 2000.0f   // W_h2h int8 scale

__device__ __forceinline__ float bf2f(u16 s) { return __uint_as_float(((unsigned)s) << 16); }
__device__ __forceinline__ u16 f2bf(float f) {
    unsigned u = __float_as_uint(f);
    return (u16)((u + 0x7FFFu + ((u >> 16) & 1u)) >> 16);
}
__device__ __forceinline__ int q8i(float x, float s) {
    float v = fminf(fmaxf(x * s, -127.f), 127.f);
    return __float2int_rn(v);
}
__device__ __forceinline__ float fast_tanh(float x) {
    float e = __expf(2.f * x);
    return 1.f - 2.f / (e + 1.f);
}
__device__ __forceinline__ float fast_sig(float x) { return 1.f / (1.f + __expf(-x)); }
__device__ __forceinline__ float ptanh(float x) {
    float x2 = x * x;
    float r = (x * (27.f + x2)) * __frcp_rn(27.f + 9.f * x2);
    return fminf(fmaxf(r, -1.f), 1.f);
}

// ---------------- prep: weight conversions + barrier-flag zeroing ----------------
__global__ void prep_weights(const float* __restrict__ W_h2h, const float* __restrict__ W_i2h,
                             const float* __restrict__ W_ih, const float* __restrict__ W_hh,
                             const float* __restrict__ b_ih, const float* __restrict__ b_hh,
                             const float* __restrict__ W_gen,
                             char* __restrict__ Wh2h_q8, u16* __restrict__ Wi2h_bf,
                             u16* __restrict__ Wcat3, float* __restrict__ bsum,
                             u16* __restrict__ WgenP, float* __restrict__ WohT,
                             u32* __restrict__ flags) {
    int idx = blockIdx.x * 256 + threadIdx.x;  // 65536 threads
    if (idx < 65536) {
        Wh2h_q8[idx] = (char)q8i(W_h2h[idx], SW);
        Wi2h_bf[idx] = f2bf(W_i2h[idx]);
    }
    for (int i = idx; i < 16 * 16 * 4 * 64 * 8; i += 65536) {
        int j = i & 7, lane = (i >> 3) & 63, q = (i >> 9) & 3, ks = (i >> 11) & 15, ub = i >> 15;
        int lr = lane & 15, lq = lane >> 4;
        int rg = q * 256 + ub * 16 + lr;
        int k = ks * 32 + lq * 8 + j;
        float v = (k < 256) ? W_ih[(size_t)rg * 356 + k] : W_hh[(size_t)rg * 256 + (k - 256)];
        Wcat3[i] = f2bf(v);
    }
    for (int i = idx; i < 100 * 1024; i += 65536) {
        int t = i >> 10, rg = i & 1023;
        WohT[i] = W_ih[(size_t)rg * 356 + 256 + t];
    }
    if (idx < 1024) bsum[idx] = b_ih[idx] + b_hh[idx];
    if (idx < 128 * 256) {
        int r = idx >> 8, ccol = idx & 255;
        WgenP[idx] = (r < NCLS) ? f2bf(W_gen[r * 256 + ccol]) : (u16)0;
    }
    if (idx < 32 * 52) flags[idx] = 0u;  // cluster barrier counters, fresh every launch
}

// ---------------- proj_H GEMM, M=32 tile, full N=256, int8 outputs ----------------
__launch_bounds__(256)
__global__ void gemm_projH3(const float* __restrict__ bH, const u16* __restrict__ Wi2h_bf,
                            char* __restrict__ projF8, char* __restrict__ bHf8) {
    __shared__ u16 As[32 * 32];
    __shared__ u16 Bs[256 * 32];
    int mb = blockIdx.x, tid = threadIdx.x;
    int wave = tid >> 6, lane = tid & 63, lr = lane & 15, lq = lane >> 4;
    int wm = wave >> 1, wn = wave & 1;
    int b = mb >> 2;
    int t0 = (mb & 3) * 32;
    f32x4 acc[8] = {};

    for (int kc = 0; kc < 256; kc += 32) {
        __syncthreads();
        {
            int r = tid >> 3, c4 = (tid & 7) * 4;
            const float* src = bH + (size_t)(mb * 32 + r) * 256 + kc + c4;
            float4 v = *(const float4*)(src);
            u16* dst = As + r * 32 + c4;
            dst[0] = f2bf(v.x); dst[1] = f2bf(v.y); dst[2] = f2bf(v.z); dst[3] = f2bf(v.w);
            uint pk = (uint)(u8)q8i(v.x, SH) | ((uint)(u8)q8i(v.y, SH) << 8) |
                      ((uint)(u8)q8i(v.z, SH) << 16) | ((uint)(u8)q8i(v.w, SH) << 24);
            *(uint*)(bHf8 + (size_t)(mb * 32 + r) * 256 + kc + c4) = pk;
        }
        {
            int p = tid & 3;
            for (int rr = tid >> 2; rr < 256; rr += 64) {
                short8 v = *(const short8*)(Wi2h_bf + (size_t)rr * 256 + kc + p * 8);
                *(short8*)(Bs + rr * 32 + p * 8) = v;
            }
        }
        __syncthreads();
        short8 a = *reinterpret_cast<const short8*>(As + (wm * 16 + lr) * 32 + lq * 8);
        for (int ni = 0; ni < 8; ni++) {
            short8 bf = *reinterpret_cast<const short8*>(Bs + (wn * 128 + ni * 16 + lr) * 32 + lq * 8);
            acc[ni] = __builtin_amdgcn_mfma_f32_16x16x32_bf16(a, bf, acc[ni], 0, 0, 0);
        }
    }
    __syncthreads();
    char* Tt = (char*)Bs;
    {
        int ml = wm * 16 + lq * 4;
        for (int ni = 0; ni < 8; ni++) {
            int n = wn * 128 + ni * 16 + lr;
            uint pk = (uint)(u8)q8i(acc[ni][0], SP) | ((uint)(u8)q8i(acc[ni][1], SP) << 8) |
                      ((uint)(u8)q8i(acc[ni][2], SP) << 16) | ((uint)(u8)q8i(acc[ni][3], SP) << 24);
            *(uint*)(Tt + n * 32 + ml) = pk;
        }
    }
    __syncthreads();
    {
        int rr = tid;
        uint4 v0 = *(uint4*)(Tt + rr * 32);
        uint4 v1 = *(uint4*)(Tt + rr * 32 + 16);
        char* dst = projF8 + (size_t)b * 32768 + rr * 128 + t0;
        *(uint4*)(dst) = v0;
        *(uint4*)(dst + 16) = v1;
    }
}

// ---------------- persistent mega kernel: all 26 steps of attn + lstm ----------------
// 512 blocks (one per batch), 2 blocks/CU co-resident. Cluster = 16 blocks (same b>>4).
// Cross-block exchange: XcatS (LSTM A-frags) and h_cur, guarded by per-cluster
// device-scope atomic barriers (fresh counter per step*phase -> no sense reversal).
__launch_bounds__(256, 2)
__global__ void mega_steps(const char* __restrict__ projF8, const char* __restrict__ bHf8,
                           const char* __restrict__ Wh2h_q8, const float* __restrict__ b_h2h,
                           const float* __restrict__ W_score, const u16* __restrict__ Wcat3,
                           const float* __restrict__ bsum, const float* __restrict__ WohT,
                           const int* __restrict__ text, u16* XcatS,
                           float* h_cur, u16* __restrict__ hbf_all, u32* flags) {
    extern __shared__ char smem[];
    char* projL = smem;                       // [h 256][t 128] int8, 32 KB
    char* bHL = smem + 32768;                 // [t 128][i 256] int8, 32 KB
    float* h_s = (float*)(smem + 65536);      // 256
    float* ph = h_s + 256;                    // 256
    float* ws_s = ph + 256;                   // 256
    float* epart = ws_s + 256;                // 512 = [t 128][wave 4]
    float* e_s = epart + 512;                 // 128
    float* red = e_s + 128;                   // 4
    float* cpart = red + 4;                   // 1024; aliased as gq[4][64][4] in lstm phase
    float* gq = cpart;

    int b = blockIdx.x, tid = threadIdx.x;
    int wave = tid >> 6, lane = tid & 63;
    int c = b >> 4, blr = b & 15;
    int lr = lane & 15, lq = lane >> 4;
    u32* flagbase = flags + c * 52;

    // one-time LDS fill of this batch's slices (64 KB)
    {
        const char* g1 = projF8 + (size_t)b * 32768;
        const char* g2 = bHf8 + (size_t)b * 32768;
        for (int i = 0; i < 8; i++) {
            int o = i * 4096 + tid * 16;
            *(uint4*)(projL + o) = *(const uint4*)(g1 + o);
            *(uint4*)(bHL + o) = *(const uint4*)(g2 + o);
        }
    }
    ws_s[tid] = W_score[tid];

    // persistent LSTM lane state: this block handles job (cluster c, unit group ub=blr);
    // wave w owns gate-exchange row r=w -> batch bgi = c*16 + lq*4 + w, unit u_ = blr*16 + lr
    int u_ = blr * 16 + lr;
    float cc = 0.f;
    float bi = bsum[u_], bfg = bsum[256 + u_], bgg = bsum[512 + u_], bo = bsum[768 + u_];

    for (int s = 0; s < NSTEP; s++) {
        // ---------- attention for batch b ----------
        float hv = (s == 0) ? 0.f : h_cur[b * 256 + tid];
        h_s[tid] = hv;
        {   // h half of XcatS (A-frag layout), value k = 256+tid
            int k = 256 + tid;
            int ks = k >> 5, klq = (k >> 3) & 3, j = k & 7;
            XcatS[(size_t)((c * 16 + ks) * 64 + klq * 16 + blr) * 8 + j] = f2bf(hv);
        }
        __syncthreads();

        if (s == 0) {
            ph[tid] = b_h2h[tid];
        } else {
            float acc = 0.f;
            const char* wrow = Wh2h_q8 + (size_t)tid * 256;
            for (int k = 0; k < 256; k += 16) {
                uint4 u = *(const uint4*)(wrow + k);
                uint w = u.x;
                acc += h_s[k + 0] * (float)(char)(w) + h_s[k + 1] * (float)(char)(w >> 8) +
                       h_s[k + 2] * (float)(char)(w >> 16) + h_s[k + 3] * (float)(char)(w >> 24);
                w = u.y;
                acc += h_s[k + 4] * (float)(char)(w) + h_s[k + 5] * (float)(char)(w >> 8) +
                       h_s[k + 6] * (float)(char)(w >> 16) + h_s[k + 7] * (float)(char)(w >> 24);
                w = u.z;
                acc += h_s[k + 8] * (float)(char)(w) + h_s[k + 9] * (float)(char)(w >> 8) +
                       h_s[k + 10] * (float)(char)(w >> 16) + h_s[k + 11] * (float)(char)(w >> 24);
                w = u.w;
                acc += h_s[k + 12] * (float)(char)(w) + h_s[k + 13] * (float)(char)(w >> 8) +
                       h_s[k + 14] * (float)(char)(w >> 16) + h_s[k + 15] * (float)(char)(w >> 24);
            }
            ph[tid] = acc * (1.f / SW) + b_h2h[tid];
        }
        __syncthreads();

        // e[t] = sum_h tanh(projL/SP + ph[h]) * Ws[h]
        {
            int tq = tid & 15, hg = tid >> 4;
            int t0 = tq * 8;
            float a8[8] = {};
            for (int hh = 0; hh < 16; hh++) {
                int R = hg * 16 + hh;
                uint2 uu = *(const uint2*)(projL + R * 128 + t0);
                float phv = ph[R], wv = ws_s[R];
                uint w = uu.x;
                a8[0] += ptanh((float)(char)(w) * (1.f / SP) + phv) * wv;
                a8[1] += ptanh((float)(char)(w >> 8) * (1.f / SP) + phv) * wv;
                a8[2] += ptanh((float)(char)(w >> 16) * (1.f / SP) + phv) * wv;
                a8[3] += ptanh((float)(char)(w >> 24) * (1.f / SP) + phv) * wv;
                w = uu.y;
                a8[4] += ptanh((float)(char)(w) * (1.f / SP) + phv) * wv;
                a8[5] += ptanh((float)(char)(w >> 8) * (1.f / SP) + phv) * wv;
                a8[6] += ptanh((float)(char)(w >> 16) * (1.f / SP) + phv) * wv;
                a8[7] += ptanh((float)(char)(w >> 24) * (1.f / SP) + phv) * wv;
            }
            // reduce over the 4 hg groups within this wave (lanes differ by 16,32)
            for (int j = 0; j < 8; j++) {
                float v = a8[j];
                v += __shfl_xor(v, 16);
                v += __shfl_xor(v, 32);
                a8[j] = v;
            }
            if (lane < 16) {
                for (int j = 0; j < 8; j++) epart[(t0 + j) * 4 + wave] = a8[j];
            }
        }
        __syncthreads();
        if (tid < 128)
            e_s[tid] = epart[tid * 4 + 0] + epart[tid * 4 + 1] +
                       epart[tid * 4 + 2] + epart[tid * 4 + 3];
        __syncthreads();

        // softmax over t
        if (tid < 64) {
            float v = fmaxf(e_s[tid], e_s[tid + 64]);
            for (int o = 32; o >= 1; o >>= 1) v = fmaxf(v, __shfl_down(v, o));
            if (tid == 0) red[0] = v;
        }
        __syncthreads();
        float mx = red[0];
        if (tid < 128) e_s[tid] = __expf(e_s[tid] - mx);
        __syncthreads();
        if (tid < 64) {
            float v = e_s[tid] + e_s[tid + 64];
            for (int o = 32; o >= 1; o >>= 1) v += __shfl_down(v, o);
            if (tid == 0) red[1] = 1.f / v;
        }
        __syncthreads();
        float rinv = red[1];

        // context[i] = (sum_t alpha_t * bHL[t][i]) * rinv / SH
        {
            int cidx = lane, ts = wave;
            float a4[4] = {};
            const char* bb = bHL + cidx * 4;
            for (int it = 0; it < 32; it++) {
                int t = it * 4 + ts;
                uint u = *(const uint*)(bb + t * 256);
                float al = e_s[t];
                a4[0] += al * (float)(char)(u);
                a4[1] += al * (float)(char)(u >> 8);
                a4[2] += al * (float)(char)(u >> 16);
                a4[3] += al * (float)(char)(u >> 24);
            }
            for (int j = 0; j < 4; j++) cpart[(cidx * 4 + j) * 4 + ts] = a4[j];
        }
        __syncthreads();
        {
            float sm = cpart[tid * 4 + 0] + cpart[tid * 4 + 1] +
                       cpart[tid * 4 + 2] + cpart[tid * 4 + 3];
            int k = tid;
            int ks = k >> 5, klq = (k >> 3) & 3, j = k & 7;
            XcatS[(size_t)((c * 16 + ks) * 64 + klq * 16 + blr) * 8 + j] =
                f2bf(sm * rinv * (1.f / SH));
        }

        // ---------- cluster barrier: Xcat ready ----------
        {
            u32* flag = flagbase + s * 2 + 0;
            __syncthreads();
            __threadfence();
            if (tid == 0) {
                atomicAdd(flag, 1u);
                while (atomicAdd(flag, 0u) < 16u) __builtin_amdgcn_s_sleep(2);
            }
            __syncthreads();
            __threadfence();
        }

        // ---------- LSTM job (c, ub=blr); wave = gate quadrant ----------
        {
            f32x4 acc1 = {0.f, 0.f, 0.f, 0.f};
            for (int ks = 0; ks < 16; ks++) {
                short8 a = *(const short8*)(XcatS + (size_t)((c * 16 + ks) * 64 + lane) * 8);
                const u16* wb = Wcat3 + ((size_t)((blr * 16 + ks) * 4 + wave)) * 512 + lane * 8;
                short8 bb = *(const short8*)(wb);
                acc1 = __builtin_amdgcn_mfma_f32_16x16x32_bf16(a, bb, acc1, 0, 0, 0);
            }
            // exchange quadrants via LDS: gq[q 4][lane 64][r 4]
            float4 gw;
            gw.x = acc1[0]; gw.y = acc1[1]; gw.z = acc1[2]; gw.w = acc1[3];
            *(float4*)(gq + wave * 256 + lane * 4) = gw;
        }
        __syncthreads();
        {
            int w = wave;
            float gi = gq[0 + lane * 4 + w];
            float gf = gq[256 + lane * 4 + w];
            float gg = gq[512 + lane * 4 + w];
            float go = gq[768 + lane * 4 + w];
            int bgi = c * 16 + lq * 4 + w;
            int tgt = text[bgi * NSTEP + s];
            const float* wt = WohT + (size_t)tgt * 1024;
            gi += bi + wt[u_];
            gf += bfg + wt[256 + u_];
            gg += bgg + wt[512 + u_];
            go += bo + wt[768 + u_];
            float cn = fast_sig(gf) * cc + fast_sig(gi) * fast_tanh(gg);
            float hn = fast_sig(go) * fast_tanh(cn);
            cc = cn;
            h_cur[bgi * 256 + u_] = hn;
            hbf_all[(size_t)s * NB * NH + (size_t)bgi * 256 + u_] = f2bf(hn);
        }

        // ---------- cluster barrier: h ready (skip on last step) ----------
        if (s < NSTEP - 1) {
            u32* flag = flagbase + s * 2 + 1;
            __syncthreads();
            __threadfence();
            if (tid == 0) {
                atomicAdd(flag, 1u);
                while (atomicAdd(flag, 0u) < 16u) __builtin_amdgcn_s_sleep(2);
            }
            __syncthreads();
            __threadfence();
        }
    }
}

// ---------------- final logits ----------------
__launch_bounds__(256)
__global__ void gen_logits(const u16* __restrict__ hbf_all, const u16* __restrict__ WgenP,
                           const float* __restrict__ b_gen, float* __restrict__ out) {
    __shared__ u16 As[32 * 32];
    __shared__ u16 Bs[128 * 32];
    int mb = blockIdx.x;
    int tid = threadIdx.x;
    int wave = tid >> 6, lane = tid & 63, lr = lane & 15, lq = lane >> 4;
    int wm = wave >> 1, wn = wave & 1;
    f32x4 acc[4] = {};
    for (int kc = 0; kc < 256; kc += 32) {
        __syncthreads();
        {
            int r = tid >> 3, c4 = (tid & 7) * 4;
            *(ushort4*)(As + r * 32 + c4) =
                *(const ushort4*)(hbf_all + (size_t)(mb * 32 + r) * 256 + kc + c4);
        }
        {
            int r = tid >> 1, h16 = (tid & 1) * 16;
            const u16* src = WgenP + (size_t)r * 256 + kc + h16;
            u16* d = Bs + r * 32 + h16;
            *(ushort4*)(d) = *(const ushort4*)(src);
            *(ushort4*)(d + 4) = *(const ushort4*)(src + 4);
            *(ushort4*)(d + 8) = *(const ushort4*)(src + 8);
            *(ushort4*)(d + 12) = *(const ushort4*)(src + 12);
        }
        __syncthreads();
        short8 a = *reinterpret_cast<const short8*>(As + (wm * 16 + lr) * 32 + lq * 8);
        for (int ni = 0; ni < 4; ni++) {
            short8 bb = *reinterpret_cast<const short8*>(Bs + (wn * 64 + ni * 16 + lr) * 32 + lq * 8);
            acc[ni] = __builtin_amdgcn_mfma_f32_16x16x32_bf16(a, bb, acc[ni], 0, 0, 0);
        }
    }
    for (int ni = 0; ni < 4; ni++) {
        int cidx = wn * 64 + ni * 16 + lr;
        if (cidx >= NCLS) continue;
        float bg = b_gen[cidx];
        int mbase = mb * 32 + wm * 16 + lq * 4;
        for (int r = 0; r < 4; r++) {
            int mm = mbase + r;
            int s = mm >> 9;
            int bb_ = mm & 511;
            float v = (cidx == 3) ? -10000.f : (acc[ni][r] + bg);
            out[(size_t)bb_ * (NSTEP * NCLS) + s * NCLS + cidx] = v;
        }
    }
}

extern "C" void kernel_launch(void* const* d_in, const int* in_sizes, int n_in,
                              void* d_out, int out_size, void* d_ws, size_t ws_size,
                              hipStream_t stream) {
    const float* batch_H = (const float*)d_in[0];
    const int* text = (const int*)d_in[1];
    const float* W_i2h = (const float*)d_in[3];
    const float* W_h2h = (const float*)d_in[4];
    const float* b_h2h = (const float*)d_in[5];
    const float* W_score = (const float*)d_in[6];
    const float* W_ih = (const float*)d_in[7];
    const float* W_hh = (const float*)d_in[8];
    const float* b_ih = (const float*)d_in[9];
    const float* b_hh = (const float*)d_in[10];
    const float* W_gen = (const float*)d_in[11];
    const float* b_gen = (const float*)d_in[12];
    float* out = (float*)d_out;

    char* ws = (char*)d_ws;
    size_t off = 0;
    auto alloc = [&](size_t bytes) {
        void* p = ws + off;
        off += (bytes + 255) & ~(size_t)255;
        return p;
    };
    char* projF8 = (char*)alloc((size_t)16777216);    // [b][h][t] int8
    char* bHf8 = (char*)alloc((size_t)16777216);      // [b][t][i] int8
    char* Wh2h_q8 = (char*)alloc(65536);
    u16* Wi2h_bf = (u16*)alloc(65536 * 2);
    u16* Wcat3 = (u16*)alloc((size_t)524288 * 2);     // frag-swizzled LSTM weights
    float* bsum = (float*)alloc(1024 * 4);
    u16* WgenP = (u16*)alloc(32768 * 2);
    float* WohT = (float*)alloc((size_t)102400 * 4);  // [100][1024]
    u16* XcatS = (u16*)alloc((size_t)262144 * 2);     // A-frag-swizzled LSTM input
    float* h_cur = (float*)alloc((size_t)NB * NH * 4);
    u16* hbf_all = (u16*)alloc((size_t)NSTEP * NB * NH * 2);
    u32* flags = (u32*)alloc(32 * 52 * 4);            // cluster barrier counters

    // dyn-LDS size for mega_steps: 64 KB int8 slices + 9744 B float buffers
    const int MEGA_LDS = 65536 + 2436 * 4;
    hipFuncSetAttribute((const void*)mega_steps,
                        hipFuncAttributeMaxDynamicSharedMemorySize, MEGA_LDS);

    prep_weights<<<256, 256, 0, stream>>>(W_h2h, W_i2h, W_ih, W_hh, b_ih, b_hh, W_gen,
                                          Wh2h_q8, Wi2h_bf, Wcat3, bsum, WgenP, WohT, flags);
    gemm_projH3<<<2048, 256, 0, stream>>>(batch_H, Wi2h_bf, projF8, bHf8);
    mega_steps<<<512, 256, MEGA_LDS, stream>>>(projF8, bHf8, Wh2h_q8, b_h2h, W_score,
                                               Wcat3, bsum, WohT, text, XcatS, h_cur,
                                               hbf_all, flags);
    gen_logits<<<416, 256, 0, stream>>>(hbf_all, WgenP, b_gen, out);
}

// Round 5
// 859.270 us; speedup vs baseline: 5.0354x; 5.0354x over previous
//
#include <hip/hip_runtime.h>
#include <stdint.h>

typedef unsigned short u16;
typedef unsigned char u8;
typedef unsigned int u32;
typedef __attribute__((ext_vector_type(8))) short short8;
typedef __attribute__((ext_vector_type(4))) float f32x4;

#define NSTEP 26
#define NB 512
#define NT 128
#define NH 256
#define NCLS 100

#define SP 32.0f     // proj_H int8 scale
#define SH 24.0f     // batch_H int8 scale
#define SW 2000.0f   // W_h2h int8 scale

__device__ __forceinline__ float bf2f(u16 s) { return __uint_as_float(((unsigned)s) << 16); }
__device__ __forceinline__ u16 f2bf(float f) {
    unsigned u = __float_as_uint(f);
    return (u16)((u + 0x7FFFu + ((u >> 16) & 1u)) >> 16);
}
__device__ __forceinline__ int q8i(float x, float s) {
    float v = fminf(fmaxf(x * s, -127.f), 127.f);
    return __float2int_rn(v);
}
__device__ __forceinline__ float fast_tanh(float x) {
    float e = __expf(2.f * x);
    return 1.f - 2.f / (e + 1.f);
}
__device__ __forceinline__ float fast_sig(float x) { return 1.f / (1.f + __expf(-x)); }
// odd deg-7 poly tanh, input clamped to [-3,3], output clamped to [-1,1].
// |err| <= ~0.016 abs; zero transcendental ops (all full-rate VALU).
__device__ __forceinline__ float poly_tanh(float x) {
    x = fminf(fmaxf(x, -3.0f), 3.0f);
    float u = x * x;
    float p = fmaf(fmaf(fmaf(-0.0016249f, u, 0.031520f), u, -0.222110f), u, 0.962117f);
    float t = x * p;
    return fminf(fmaxf(t, -1.0f), 1.0f);
}
// async global->LDS, 16B per lane (lds dst = uniform base + lane*16).
__device__ __forceinline__ void async_g2l(const void* g, void* l) {
    __builtin_amdgcn_global_load_lds((const __attribute__((address_space(1))) u32*)g,
                                     (__attribute__((address_space(3))) u32*)l, 16, 0, 0);
}

// ---------------- prep: weight conversions ----------------
__global__ void prep_weights(const float* __restrict__ W_h2h, const float* __restrict__ W_i2h,
                             const float* __restrict__ W_ih, const float* __restrict__ W_hh,
                             const float* __restrict__ b_ih, const float* __restrict__ b_hh,
                             const float* __restrict__ W_gen,
                             char* __restrict__ Wh2h_q8, u16* __restrict__ Wi2h_bf,
                             u16* __restrict__ Wcat3, float* __restrict__ bsum,
                             u16* __restrict__ WgenP, float* __restrict__ WohT) {
    int idx = blockIdx.x * 256 + threadIdx.x;  // 65536 threads
    if (idx < 65536) {
        Wh2h_q8[idx] = (char)q8i(W_h2h[idx], SW);
        Wi2h_bf[idx] = f2bf(W_i2h[idx]);
    }
    for (int i = idx; i < 16 * 16 * 4 * 64 * 8; i += 65536) {
        int j = i & 7, lane = (i >> 3) & 63, q = (i >> 9) & 3, ks = (i >> 11) & 15, ub = i >> 15;
        int lr = lane & 15, lq = lane >> 4;
        int rg = q * 256 + ub * 16 + lr;
        int k = ks * 32 + lq * 8 + j;
        float v = (k < 256) ? W_ih[(size_t)rg * 356 + k] : W_hh[(size_t)rg * 256 + (k - 256)];
        Wcat3[i] = f2bf(v);
    }
    for (int i = idx; i < 100 * 1024; i += 65536) {
        int t = i >> 10, rg = i & 1023;
        WohT[i] = W_ih[(size_t)rg * 356 + 256 + t];
    }
    if (idx < 1024) bsum[idx] = b_ih[idx] + b_hh[idx];
    if (idx < 128 * 256) {
        int r = idx >> 8, ccol = idx & 255;
        WgenP[idx] = (r < NCLS) ? f2bf(W_gen[r * 256 + ccol]) : (u16)0;
    }
}

// ---------------- proj_H GEMM: double-buffered, async-B, 1 barrier/K-step ----------------
// grid 2048: block mb covers m in [mb*32, mb*32+32) (m = b*128 + t), all 256 n (=h).
__launch_bounds__(256)
__global__ void gemm_projH4(const float* __restrict__ bH, const u16* __restrict__ Wi2h_bf,
                            char* __restrict__ projF8, char* __restrict__ bHf8) {
    __shared__ u16 As[2][1024];   // [buf][32 rows x 32 k]
    __shared__ u16 Bs[2][8192];   // [buf][256 rows x 32 k]; Bs[0] aliased as Tt in epilogue
    int mb = blockIdx.x, tid = threadIdx.x;
    int wave = tid >> 6, lane = tid & 63, lr = lane & 15, lq = lane >> 4;
    int wm = wave >> 1, wn = wave & 1;
    int b = mb >> 2;
    int t0 = (mb & 3) * 32;
    int ar = tid >> 3, ac4 = (tid & 7) * 4;  // this thread's A element (row, 4-col)
    const float* asrc = bH + (size_t)(mb * 32 + ar) * 256 + ac4;
    f32x4 acc[8] = {};

    // stage B(kc) -> Bs[buf] via async (4 chunks of 16 rows per wave)
    auto stageB = [&](int kc, int buf) {
        int rr0 = wave * 64 + (lane >> 2) * 4;  // handled below per chunk
        (void)rr0;
        for (int i = 0; i < 4; i++) {
            int chunk = wave * 4 + i;             // 16 rows each
            int row = chunk * 16 + (lane >> 2);
            const u16* g = Wi2h_bf + (size_t)row * 256 + kc * 32 + (lane & 3) * 8;
            async_g2l(g, (char*)Bs[buf] + chunk * 1024 + lane * 16);
        }
    };
    // write prefetched A regs into As[buf] + emit bHf8 once per element
    auto writeA = [&](int kc, int buf, float4 v) {
        u16* dst = As[buf] + ar * 32 + ac4;
        dst[0] = f2bf(v.x); dst[1] = f2bf(v.y); dst[2] = f2bf(v.z); dst[3] = f2bf(v.w);
        uint pk = (uint)(u8)q8i(v.x, SH) | ((uint)(u8)q8i(v.y, SH) << 8) |
                  ((uint)(u8)q8i(v.z, SH) << 16) | ((uint)(u8)q8i(v.w, SH) << 24);
        *(uint*)(bHf8 + (size_t)(mb * 32 + ar) * 256 + kc * 32 + ac4) = pk;
    };

    float4 aval = *(const float4*)(asrc);            // A(0)
    stageB(0, 0);
    writeA(0, 0, aval);
    aval = *(const float4*)(asrc + 32);              // A(1)
    __syncthreads();

    for (int kc = 0; kc < 8; kc++) {
        int cur = kc & 1, nxt = cur ^ 1;
        if (kc < 7) stageB(kc + 1, nxt);
        short8 a = *reinterpret_cast<const short8*>(As[cur] + (wm * 16 + lr) * 32 + lq * 8);
        for (int ni = 0; ni < 8; ni++) {
            short8 bf = *reinterpret_cast<const short8*>(
                Bs[cur] + (wn * 128 + ni * 16 + lr) * 32 + lq * 8);
            acc[ni] = __builtin_amdgcn_mfma_f32_16x16x32_bf16(a, bf, acc[ni], 0, 0, 0);
        }
        if (kc < 7) {
            writeA(kc + 1, nxt, aval);
            if (kc < 6) aval = *(const float4*)(asrc + (kc + 2) * 32);
            __syncthreads();   // As[nxt] visible + asyncB(kc+1) drained (hidden under MFMA)
        }
    }
    __syncthreads();
    char* Tt = (char*)Bs[0];  // [n=256][tl=32] int8
    {
        int ml = wm * 16 + lq * 4;
        for (int ni = 0; ni < 8; ni++) {
            int n = wn * 128 + ni * 16 + lr;
            uint pk = (uint)(u8)q8i(acc[ni][0], SP) | ((uint)(u8)q8i(acc[ni][1], SP) << 8) |
                      ((uint)(u8)q8i(acc[ni][2], SP) << 16) | ((uint)(u8)q8i(acc[ni][3], SP) << 24);
            *(uint*)(Tt + n * 32 + ml) = pk;
        }
    }
    __syncthreads();
    {
        int rr = tid;
        uint4 v0 = *(uint4*)(Tt + rr * 32);
        uint4 v1 = *(uint4*)(Tt + rr * 32 + 16);
        char* dst = projF8 + (size_t)b * 32768 + rr * 128 + t0;
        *(uint4*)(dst) = v0;
        *(uint4*)(dst + 16) = v1;
    }
}

// ---------------- per-step fused attention: both slices LDS-resident ----------------
// dyn LDS: projL 33792 | bHL 33792 | floats 9760  => 77344 B, 2 blocks/CU
__launch_bounds__(256)
__global__ void attn_step5(const float* __restrict__ h_all, const char* __restrict__ Wh2h_q8,
                           const float* __restrict__ b_h2h, const float* __restrict__ W_score,
                           const char* __restrict__ projF8, const char* __restrict__ bHf8,
                           u16* __restrict__ XcatS, int step) {
    extern __shared__ char smem[];
    char* projL = smem;                        // 32 chunks x (1024 + 32 pad)
    char* bHL = smem + 33792;                  // 32 chunks x (1024 + 32 pad)
    float* h_s = (float*)(smem + 67584);       // 256
    float* ph = h_s + 256;                     // 256
    float* ws_s = ph + 256;                    // 256
    float* epart = ws_s + 256;                 // 512 = [t 128][wave 4]
    float* e_s = epart + 512;                  // 128
    float* red = e_s + 128;                    // 8
    float* cpart = red + 8;                    // 1024

    int b = blockIdx.x, tid = threadIdx.x;
    int wave = tid >> 6, lane = tid & 63;
    int btile = b >> 4, blr = b & 15;

    // async prefetch: projF8[b] and bHf8[b] (32 KB each)
    {
        const char* g1 = projF8 + (size_t)b * 32768;
        const char* g2 = bHf8 + (size_t)b * 32768;
        for (int i = 0; i < 8; i++) {
            int c = wave * 8 + i;
            async_g2l(g1 + c * 1024 + lane * 16, projL + c * 1056 + lane * 16);
            async_g2l(g2 + c * 1024 + lane * 16, bHL + c * 1056 + lane * 16);
        }
    }

    float hv = (step > 0) ? h_all[(size_t)(step - 1) * NB * NH + b * NH + tid] : 0.f;
    h_s[tid] = hv;
    ws_s[tid] = W_score[tid];
    {   // h half of XcatS (A-frag layout), value k = 256+tid
        int k = 256 + tid;
        int ks = k >> 5, klq = (k >> 3) & 3, j = k & 7;
        XcatS[(size_t)((btile * 16 + ks) * 64 + klq * 16 + blr) * 8 + j] = f2bf(hv);
    }
    __syncthreads();

    // ph[u] = b_h2h[u] + (h . Wq8[u,:]) / SW   (global Wh2h reads, L1/L2-hot)
    if (step == 0) {
        ph[tid] = b_h2h[tid];
    } else {
        float acc = 0.f;
        const char* wrow = Wh2h_q8 + (size_t)tid * 256;
        for (int k = 0; k < 256; k += 16) {
            uint4 u = *(const uint4*)(wrow + k);
            uint w = u.x;
            acc += h_s[k + 0] * (float)(char)(w) + h_s[k + 1] * (float)(char)(w >> 8) +
                   h_s[k + 2] * (float)(char)(w >> 16) + h_s[k + 3] * (float)(char)(w >> 24);
            w = u.y;
            acc += h_s[k + 4] * (float)(char)(w) + h_s[k + 5] * (float)(char)(w >> 8) +
                   h_s[k + 6] * (float)(char)(w >> 16) + h_s[k + 7] * (float)(char)(w >> 24);
            w = u.z;
            acc += h_s[k + 8] * (float)(char)(w) + h_s[k + 9] * (float)(char)(w >> 8) +
                   h_s[k + 10] * (float)(char)(w >> 16) + h_s[k + 11] * (float)(char)(w >> 24);
            w = u.w;
            acc += h_s[k + 12] * (float)(char)(w) + h_s[k + 13] * (float)(char)(w >> 8) +
                   h_s[k + 14] * (float)(char)(w >> 16) + h_s[k + 15] * (float)(char)(w >> 24);
        }
        ph[tid] = acc * (1.f / SW) + b_h2h[tid];
    }
    __syncthreads();

    // e[t] = sum_h poly_tanh(projL/SP + ph[h]) * Ws[h]
    {
        int tq = tid & 15, hg = tid >> 4;
        int t0 = tq * 8;
        float a8[8] = {};
        for (int hh = 0; hh < 16; hh++) {
            int R = hg * 16 + hh;
            const char* p = projL + (R >> 3) * 1056 + (R & 7) * 128 + t0;
            uint2 uu = *(const uint2*)(p);
            float phv = ph[R], wv = ws_s[R];
            uint w = uu.x;
            a8[0] += poly_tanh(fmaf((float)(char)(w), 1.f / SP, phv)) * wv;
            a8[1] += poly_tanh(fmaf((float)(char)(w >> 8), 1.f / SP, phv)) * wv;
            a8[2] += poly_tanh(fmaf((float)(char)(w >> 16), 1.f / SP, phv)) * wv;
            a8[3] += poly_tanh(fmaf((float)(char)(w >> 24), 1.f / SP, phv)) * wv;
            w = uu.y;
            a8[4] += poly_tanh(fmaf((float)(char)(w), 1.f / SP, phv)) * wv;
            a8[5] += poly_tanh(fmaf((float)(char)(w >> 8), 1.f / SP, phv)) * wv;
            a8[6] += poly_tanh(fmaf((float)(char)(w >> 16), 1.f / SP, phv)) * wv;
            a8[7] += poly_tanh(fmaf((float)(char)(w >> 24), 1.f / SP, phv)) * wv;
        }
        // reduce the 4 hg-groups within this wave (lanes differ by 16, 32)
        for (int j = 0; j < 8; j++) {
            float v = a8[j];
            v += __shfl_xor(v, 16);
            v += __shfl_xor(v, 32);
            a8[j] = v;
        }
        if (lane < 16) {
            for (int j = 0; j < 8; j++) epart[(t0 + j) * 4 + wave] = a8[j];
        }
    }
    __syncthreads();
    if (tid < 128)
        e_s[tid] = epart[tid * 4 + 0] + epart[tid * 4 + 1] +
                   epart[tid * 4 + 2] + epart[tid * 4 + 3];
    __syncthreads();

    // softmax over t
    if (tid < 64) {
        float v = fmaxf(e_s[tid], e_s[tid + 64]);
        for (int o = 32; o >= 1; o >>= 1) v = fmaxf(v, __shfl_down(v, o));
        if (tid == 0) red[0] = v;
    }
    __syncthreads();
    float mx = red[0];
    if (tid < 128) e_s[tid] = __expf(e_s[tid] - mx);
    __syncthreads();
    if (tid < 64) {
        float v = e_s[tid] + e_s[tid + 64];
        for (int o = 32; o >= 1; o >>= 1) v += __shfl_down(v, o);
        if (tid == 0) red[1] = 1.f / v;
    }
    __syncthreads();
    float rinv = red[1];

    // context[i] = (sum_t alpha_t * bHL[t][i]) * rinv / SH   (bHL chunk: 4 t-rows/chunk)
    {
        int cidx = lane, ts = wave;
        float a4[4] = {};
        for (int it = 0; it < 32; it++) {
            int t = it * 4 + ts;
            uint u = *(const uint*)(bHL + (t >> 2) * 1056 + (t & 3) * 256 + cidx * 4);
            float al = e_s[t];
            a4[0] += al * (float)(char)(u);
            a4[1] += al * (float)(char)(u >> 8);
            a4[2] += al * (float)(char)(u >> 16);
            a4[3] += al * (float)(char)(u >> 24);
        }
        for (int j = 0; j < 4; j++) cpart[(cidx * 4 + j) * 4 + ts] = a4[j];
    }
    __syncthreads();
    {
        float sm = cpart[tid * 4 + 0] + cpart[tid * 4 + 1] +
                   cpart[tid * 4 + 2] + cpart[tid * 4 + 3];
        int k = tid;
        int ks = k >> 5, klq = (k >> 3) & 3, j = k & 7;
        XcatS[(size_t)((btile * 16 + ks) * 64 + klq * 16 + blr) * 8 + j] =
            f2bf(sm * rinv * (1.f / SH));
    }
}

// ---------------- per-step LSTM: 512 blocks x 64 threads (all CUs busy) ----------------
__launch_bounds__(64)
__global__ void lstm_step5(const u16* __restrict__ XcatS, const u16* __restrict__ Wcat3,
                           const float* __restrict__ bsum, const float* __restrict__ WohT,
                           const int* __restrict__ text, float* __restrict__ c_st,
                           float* __restrict__ h_all, u16* __restrict__ hbf_all, int step) {
    int lane = threadIdx.x;
    int lr = lane & 15, lq = lane >> 4;
    int job = blockIdx.x;              // 512 jobs
    int mt = job >> 4;                 // m-tile: batches mt*16..+16
    int ub = job & 15;                 // unit group: units ub*16..+16
    f32x4 acc[4] = {};

    for (int ks = 0; ks < 16; ks++) {
        short8 a = *(const short8*)(XcatS + (size_t)((mt * 16 + ks) * 64 + lane) * 8);
        const u16* wb = Wcat3 + (size_t)((ub * 16 + ks) * 4) * 512 + lane * 8;
        short8 b0 = *(const short8*)(wb);
        short8 b1 = *(const short8*)(wb + 512);
        short8 b2 = *(const short8*)(wb + 1024);
        short8 b3 = *(const short8*)(wb + 1536);
        acc[0] = __builtin_amdgcn_mfma_f32_16x16x32_bf16(a, b0, acc[0], 0, 0, 0);
        acc[1] = __builtin_amdgcn_mfma_f32_16x16x32_bf16(a, b1, acc[1], 0, 0, 0);
        acc[2] = __builtin_amdgcn_mfma_f32_16x16x32_bf16(a, b2, acc[2], 0, 0, 0);
        acc[3] = __builtin_amdgcn_mfma_f32_16x16x32_bf16(a, b3, acc[3], 0, 0, 0);
    }

    int u = ub * 16 + lr;
    float bi = bsum[u], bf = bsum[256 + u], bg = bsum[512 + u], bo = bsum[768 + u];
    for (int r = 0; r < 4; r++) {
        int bgi = mt * 16 + lq * 4 + r;
        int tgt = text[bgi * NSTEP + step];
        const float* wt = WohT + (size_t)tgt * 1024;
        float gi = acc[0][r] + bi + wt[u];
        float gf = acc[1][r] + bf + wt[256 + u];
        float gg = acc[2][r] + bg + wt[512 + u];
        float go = acc[3][r] + bo + wt[768 + u];
        float cold = (step > 0) ? c_st[(size_t)bgi * 256 + u] : 0.f;
        float cn = fast_sig(gf) * cold + fast_sig(gi) * fast_tanh(gg);
        float hn = fast_sig(go) * fast_tanh(cn);
        c_st[(size_t)bgi * 256 + u] = cn;
        h_all[(size_t)step * NB * NH + (size_t)bgi * 256 + u] = hn;
        hbf_all[(size_t)step * NB * NH + (size_t)bgi * 256 + u] = f2bf(hn);
    }
}

// ---------------- final logits ----------------
__launch_bounds__(256)
__global__ void gen_logits(const u16* __restrict__ hbf_all, const u16* __restrict__ WgenP,
                           const float* __restrict__ b_gen, float* __restrict__ out) {
    __shared__ u16 As[32 * 32];
    __shared__ u16 Bs[128 * 32];
    int mb = blockIdx.x;
    int tid = threadIdx.x;
    int wave = tid >> 6, lane = tid & 63, lr = lane & 15, lq = lane >> 4;
    int wm = wave >> 1, wn = wave & 1;
    f32x4 acc[4] = {};
    for (int kc = 0; kc < 256; kc += 32) {
        __syncthreads();
        {
            int r = tid >> 3, c4 = (tid & 7) * 4;
            *(ushort4*)(As + r * 32 + c4) =
                *(const ushort4*)(hbf_all + (size_t)(mb * 32 + r) * 256 + kc + c4);
        }
        {
            int r = tid >> 1, h16 = (tid & 1) * 16;
            const u16* src = WgenP + (size_t)r * 256 + kc + h16;
            u16* d = Bs + r * 32 + h16;
            *(ushort4*)(d) = *(const ushort4*)(src);
            *(ushort4*)(d + 4) = *(const ushort4*)(src + 4);
            *(ushort4*)(d + 8) = *(const ushort4*)(src + 8);
            *(ushort4*)(d + 12) = *(const ushort4*)(src + 12);
        }
        __syncthreads();
        short8 a = *reinterpret_cast<const short8*>(As + (wm * 16 + lr) * 32 + lq * 8);
        for (int ni = 0; ni < 4; ni++) {
            short8 bb = *reinterpret_cast<const short8*>(Bs + (wn * 64 + ni * 16 + lr) * 32 + lq * 8);
            acc[ni] = __builtin_amdgcn_mfma_f32_16x16x32_bf16(a, bb, acc[ni], 0, 0, 0);
        }
    }
    for (int ni = 0; ni < 4; ni++) {
        int cidx = wn * 64 + ni * 16 + lr;
        if (cidx >= NCLS) continue;
        float bg = b_gen[cidx];
        int mbase = mb * 32 + wm * 16 + lq * 4;
        for (int r = 0; r < 4; r++) {
            int mm = mbase + r;
            int s = mm >> 9;
            int bb_ = mm & 511;
            float v = (cidx == 3) ? -10000.f : (acc[ni][r] + bg);
            out[(size_t)bb_ * (NSTEP * NCLS) + s * NCLS + cidx] = v;
        }
    }
}

extern "C" void kernel_launch(void* const* d_in, const int* in_sizes, int n_in,
                              void* d_out, int out_size, void* d_ws, size_t ws_size,
                              hipStream_t stream) {
    const float* batch_H = (const float*)d_in[0];
    const int* text = (const int*)d_in[1];
    const float* W_i2h = (const float*)d_in[3];
    const float* W_h2h = (const float*)d_in[4];
    const float* b_h2h = (const float*)d_in[5];
    const float* W_score = (const float*)d_in[6];
    const float* W_ih = (const float*)d_in[7];
    const float* W_hh = (const float*)d_in[8];
    const float* b_ih = (const float*)d_in[9];
    const float* b_hh = (const float*)d_in[10];
    const float* W_gen = (const float*)d_in[11];
    const float* b_gen = (const float*)d_in[12];
    float* out = (float*)d_out;

    char* ws = (char*)d_ws;
    size_t off = 0;
    auto alloc = [&](size_t bytes) {
        void* p = ws + off;
        off += (bytes + 255) & ~(size_t)255;
        return p;
    };
    char* projF8 = (char*)alloc((size_t)16777216);    // [b][h][t] int8
    char* bHf8 = (char*)alloc((size_t)16777216);      // [b][t][i] int8
    char* Wh2h_q8 = (char*)alloc(65536);
    u16* Wi2h_bf = (u16*)alloc(65536 * 2);
    u16* Wcat3 = (u16*)alloc((size_t)524288 * 2);     // frag-swizzled LSTM weights
    float* bsum = (float*)alloc(1024 * 4);
    u16* WgenP = (u16*)alloc(32768 * 2);
    float* WohT = (float*)alloc((size_t)102400 * 4);  // [100][1024]
    u16* XcatS = (u16*)alloc((size_t)262144 * 2);     // A-frag-swizzled LSTM input
    float* h_all = (float*)alloc((size_t)NSTEP * NB * NH * 4);
    u16* hbf_all = (u16*)alloc((size_t)NSTEP * NB * NH * 2);
    float* c_st = (float*)alloc((size_t)NB * NH * 4);

    const int ATTN_LDS = 77344;
    hipFuncSetAttribute((const void*)attn_step5,
                        hipFuncAttributeMaxDynamicSharedMemorySize, ATTN_LDS);

    prep_weights<<<256, 256, 0, stream>>>(W_h2h, W_i2h, W_ih, W_hh, b_ih, b_hh, W_gen,
                                          Wh2h_q8, Wi2h_bf, Wcat3, bsum, WgenP, WohT);
    gemm_projH4<<<2048, 256, 0, stream>>>(batch_H, Wi2h_bf, projF8, bHf8);
    for (int s = 0; s < NSTEP; s++) {
        attn_step5<<<512, 256, ATTN_LDS, stream>>>(h_all, Wh2h_q8, b_h2h, W_score,
                                                   projF8, bHf8, XcatS, s);
        lstm_step5<<<512, 64, 0, stream>>>(XcatS, Wcat3, bsum, WohT, text, c_st,
                                           h_all, hbf_all, s);
    }
    gen_logits<<<416, 256, 0, stream>>>(hbf_all, WgenP, b_gen, out);
}

// Round 6
// 744.247 us; speedup vs baseline: 5.8136x; 1.1545x over previous
//
#include <hip/hip_runtime.h>
#include <stdint.h>

typedef unsigned short u16;
typedef unsigned char u8;
typedef unsigned int u32;
typedef __attribute__((ext_vector_type(8))) short short8;
typedef __attribute__((ext_vector_type(4))) float f32x4;

#define NSTEP 26
#define NB 512
#define NT 128
#define NH 256
#define NCLS 100

#define SP 32.0f     // proj_H int8 scale
#define SH 24.0f     // batch_H int8 scale
#define SW 2000.0f   // W_h2h int8 scale
#define S8 127.0f    // h int8 scale

#if defined(__has_builtin)
#if __has_builtin(__builtin_amdgcn_sdot4)
#define HAS_SDOT4 1
#endif
#endif

__device__ __forceinline__ float bf2f(u16 s) { return __uint_as_float(((unsigned)s) << 16); }
__device__ __forceinline__ u16 f2bf(float f) {
    unsigned u = __float_as_uint(f);
    return (u16)((u + 0x7FFFu + ((u >> 16) & 1u)) >> 16);
}
__device__ __forceinline__ int q8i(float x, float s) {
    float v = fminf(fmaxf(x * s, -127.f), 127.f);
    return __float2int_rn(v);
}
__device__ __forceinline__ float fast_tanh(float x) {
    float e = __expf(2.f * x);
    return 1.f - 2.f / (e + 1.f);
}
__device__ __forceinline__ float fast_sig(float x) { return 1.f / (1.f + __expf(-x)); }
// odd deg-7 poly tanh on clamped [-3,3]; p(3)=0.996 so no output clamp needed
__device__ __forceinline__ float poly_tanh(float x) {
    x = fminf(fmaxf(x, -3.0f), 3.0f);
    float u = x * x;
    float p = fmaf(fmaf(fmaf(-0.0016249f, u, 0.031520f), u, -0.222110f), u, 0.962117f);
    return x * p;
}
__device__ __forceinline__ void async_g2l(const void* g, void* l) {
    __builtin_amdgcn_global_load_lds((const __attribute__((address_space(1))) u32*)g,
                                     (__attribute__((address_space(3))) u32*)l, 16, 0, 0);
}

// ---------------- prep: weight conversions ----------------
__global__ void prep_weights(const float* __restrict__ W_h2h, const float* __restrict__ W_i2h,
                             const float* __restrict__ W_ih, const float* __restrict__ W_hh,
                             const float* __restrict__ b_ih, const float* __restrict__ b_hh,
                             const float* __restrict__ W_gen,
                             char* __restrict__ Wh2h_q8, u16* __restrict__ Wi2h_bf,
                             u16* __restrict__ Wcat3, float* __restrict__ bsum,
                             u16* __restrict__ WgenP, float* __restrict__ WohT) {
    int idx = blockIdx.x * 256 + threadIdx.x;  // 65536 threads
    if (idx < 65536) {
        Wh2h_q8[idx] = (char)q8i(W_h2h[idx], SW);
        Wi2h_bf[idx] = f2bf(W_i2h[idx]);
    }
    for (int i = idx; i < 16 * 16 * 4 * 64 * 8; i += 65536) {
        int j = i & 7, lane = (i >> 3) & 63, q = (i >> 9) & 3, ks = (i >> 11) & 15, ub = i >> 15;
        int lr = lane & 15, lq = lane >> 4;
        int rg = q * 256 + ub * 16 + lr;
        int k = ks * 32 + lq * 8 + j;
        float v = (k < 256) ? W_ih[(size_t)rg * 356 + k] : W_hh[(size_t)rg * 256 + (k - 256)];
        Wcat3[i] = f2bf(v);
    }
    for (int i = idx; i < 100 * 1024; i += 65536) {
        int t = i >> 10, rg = i & 1023;
        WohT[i] = W_ih[(size_t)rg * 356 + 256 + t];
    }
    if (idx < 1024) bsum[idx] = b_ih[idx] + b_hh[idx];
    if (idx < 128 * 256) {
        int r = idx >> 8, ccol = idx & 255;
        WgenP[idx] = (r < NCLS) ? f2bf(W_gen[r * 256 + ccol]) : (u16)0;
    }
}

// ---------------- proj_H GEMM: 1 batch/block, 128x256, 8 waves 2x4 ----------------
__launch_bounds__(512, 3)
__global__ void gemm_projH5(const float* __restrict__ bH, const u16* __restrict__ Wi2h_bf,
                            char* __restrict__ projF8, char* __restrict__ bHf8) {
    __shared__ char gsm[49152];
    u16* As[2] = {(u16*)gsm, (u16*)(gsm + 8192)};           // [buf][128 rows x 32 k]
    u16* Bs[2] = {(u16*)(gsm + 16384), (u16*)(gsm + 32768)};// [buf][256 rows x 32 k]
    char* Tt = gsm;                                          // epilogue: [256 h][144 pad] int8

    int b = blockIdx.x, tid = threadIdx.x;
    int wave = tid >> 6, lane = tid & 63, lr = lane & 15, lq = lane >> 4;
    int wm = wave >> 2, wn = wave & 3;
    int ar = tid >> 2, part = tid & 3;   // A staging: row 0..127, col-part
    const float* asrc = bH + ((size_t)b * 128 + ar) * 256 + part * 8;
    f32x4 acc[4][4] = {};
    uint2 bh[8];

    auto stageB = [&](int kc, int buf) {
        for (int i = 0; i < 2; i++) {
            int ch = wave * 2 + i;                        // 16 chunks of 16 rows
            int row = ch * 16 + (lane >> 2);
            const u16* g = Wi2h_bf + (size_t)row * 256 + kc * 32 + (lane & 3) * 8;
            async_g2l(g, (char*)Bs[buf] + ch * 1024 + lane * 16);
        }
    };
    auto writeA = [&](int kc, int buf, float4 v0, float4 v1) {
        u16* dst = As[buf] + ar * 32 + part * 8;
        dst[0] = f2bf(v0.x); dst[1] = f2bf(v0.y); dst[2] = f2bf(v0.z); dst[3] = f2bf(v0.w);
        dst[4] = f2bf(v1.x); dst[5] = f2bf(v1.y); dst[6] = f2bf(v1.z); dst[7] = f2bf(v1.w);
        uint p0 = (uint)(u8)q8i(v0.x, SH) | ((uint)(u8)q8i(v0.y, SH) << 8) |
                  ((uint)(u8)q8i(v0.z, SH) << 16) | ((uint)(u8)q8i(v0.w, SH) << 24);
        uint p1 = (uint)(u8)q8i(v1.x, SH) | ((uint)(u8)q8i(v1.y, SH) << 8) |
                  ((uint)(u8)q8i(v1.z, SH) << 16) | ((uint)(u8)q8i(v1.w, SH) << 24);
        bh[kc].x = p0; bh[kc].y = p1;
    };

    float4 a0 = *(const float4*)(asrc);
    float4 a1 = *(const float4*)(asrc + 4);
    stageB(0, 0);
    writeA(0, 0, a0, a1);
    __syncthreads();

    for (int kc = 0; kc < 8; kc++) {
        int cur = kc & 1, nxt = cur ^ 1;
        if (kc < 7) {
            stageB(kc + 1, nxt);
            a0 = *(const float4*)(asrc + (kc + 1) * 32);
            a1 = *(const float4*)(asrc + (kc + 1) * 32 + 4);
        }
        short8 af[4];
        for (int mi = 0; mi < 4; mi++)
            af[mi] = *(const short8*)(As[cur] + (wm * 64 + mi * 16 + lr) * 32 + lq * 8);
        for (int ni = 0; ni < 4; ni++) {
            short8 bf = *(const short8*)(Bs[cur] + (wn * 64 + ni * 16 + lr) * 32 + lq * 8);
            for (int mi = 0; mi < 4; mi++)
                acc[mi][ni] = __builtin_amdgcn_mfma_f32_16x16x32_bf16(af[mi], bf, acc[mi][ni], 0, 0, 0);
        }
        if (kc < 7) writeA(kc + 1, nxt, a0, a1);
        __syncthreads();
    }

    // flush bHf8 from registers (coalesced-ish uint2 stores, off the barrier path)
    {
        char* dst0 = bHf8 + (size_t)b * 32768 + ar * 256 + part * 8;
        for (int kc = 0; kc < 8; kc++) *(uint2*)(dst0 + kc * 32) = bh[kc];
    }

    // transpose epilogue: acc -> Tt[h][t] int8 (pad 144), then coalesced store
    for (int mi = 0; mi < 4; mi++)
        for (int ni = 0; ni < 4; ni++) {
            int h = wn * 64 + ni * 16 + lr;
            int t = wm * 64 + mi * 16 + lq * 4;
            f32x4 v = acc[mi][ni];
            uint pk = (uint)(u8)q8i(v[0], SP) | ((uint)(u8)q8i(v[1], SP) << 8) |
                      ((uint)(u8)q8i(v[2], SP) << 16) | ((uint)(u8)q8i(v[3], SP) << 24);
            *(uint*)(Tt + h * 144 + t) = pk;
        }
    __syncthreads();
    {
        int h = tid >> 1, half = tid & 1;
        const char* src = Tt + h * 144 + half * 64;
        char* dst = projF8 + (size_t)b * 32768 + h * 128 + half * 64;
        uint4 v0 = *(const uint4*)(src);
        uint4 v1 = *(const uint4*)(src + 16);
        uint4 v2 = *(const uint4*)(src + 32);
        uint4 v3 = *(const uint4*)(src + 48);
        *(uint4*)(dst) = v0; *(uint4*)(dst + 16) = v1;
        *(uint4*)(dst + 32) = v2; *(uint4*)(dst + 48) = v3;
    }
}

// ---------------- per-step fused attention: L2-direct, dot4 ph, 5 barriers ----------------
__launch_bounds__(256)
__global__ void attn_step6(const u16* __restrict__ hbf_all, const char* __restrict__ h8,
                           const char* __restrict__ Wh2h_q8, const float* __restrict__ b_h2h,
                           const float* __restrict__ W_score, const char* __restrict__ projF8,
                           const char* __restrict__ bHf8, u16* __restrict__ XcatS, int step) {
    __shared__ float ph[256];
    __shared__ float ws_s[256];
    __shared__ uint4 h8s[16];
    __shared__ float epart[512];   // [t 128][wave 4]
    __shared__ float es_exp[128];
    __shared__ float red[4];
    __shared__ float cpart[1024];

    int b = blockIdx.x, tid = threadIdx.x;
    int wave = tid >> 6, lane = tid & 63;
    int btile = b >> 4, blr = b & 15;

    if (tid < 16) h8s[tid] = (step > 0) ? ((const uint4*)(h8 + (size_t)b * 256))[tid]
                                        : uint4{0, 0, 0, 0};
    ws_s[tid] = W_score[tid];
    {   // h half of XcatS (A-frag layout), value k = 256+tid (bf16 pass-through)
        u16 hvb = (step > 0) ? hbf_all[(size_t)(step - 1) * NB * NH + b * 256 + tid] : (u16)0;
        int k = 256 + tid;
        int ks = k >> 5, klq = (k >> 3) & 3, j = k & 7;
        XcatS[(size_t)((btile * 16 + ks) * 64 + klq * 16 + blr) * 8 + j] = hvb;
    }
    __syncthreads();

    // ph[u] = b_h2h[u] + (h8 . Wq8[u,:]) / (SW*S8)
    if (step == 0) {
        ph[tid] = b_h2h[tid];
    } else {
        const uint4* wrow = (const uint4*)(Wh2h_q8 + (size_t)tid * 256);
        int acc = 0;
        for (int k = 0; k < 16; k++) {
            uint4 w = wrow[k];
            uint4 hh = h8s[k];
#ifdef HAS_SDOT4
            acc = __builtin_amdgcn_sdot4((int)w.x, (int)hh.x, acc, false);
            acc = __builtin_amdgcn_sdot4((int)w.y, (int)hh.y, acc, false);
            acc = __builtin_amdgcn_sdot4((int)w.z, (int)hh.z, acc, false);
            acc = __builtin_amdgcn_sdot4((int)w.w, (int)hh.w, acc, false);
#else
            uint wv[4] = {w.x, w.y, w.z, w.w}, hv[4] = {hh.x, hh.y, hh.z, hh.w};
            for (int c = 0; c < 4; c++)
                for (int by = 0; by < 32; by += 8)
                    acc += (int)(char)(wv[c] >> by) * (int)(char)(hv[c] >> by);
#endif
        }
        ph[tid] = (float)acc * (1.f / (SW * S8)) + b_h2h[tid];
    }
    __syncthreads();

    // e[t] = sum_h poly_tanh(projF8/SP + ph[h]) * Ws[h]  (direct L2 reads, single-use data)
    {
        int tq = tid & 15, hg = tid >> 4;
        int t0 = tq * 8;
        const char* base = projF8 + (size_t)b * 32768 + t0;
        float a8[8] = {};
        for (int hh = 0; hh < 16; hh++) {
            int R = hg * 16 + hh;
            uint2 uu = *(const uint2*)(base + R * 128);
            float phv = ph[R], wv = ws_s[R];
            uint w = uu.x;
            a8[0] += poly_tanh(fmaf((float)(char)(w), 1.f / SP, phv)) * wv;
            a8[1] += poly_tanh(fmaf((float)(char)(w >> 8), 1.f / SP, phv)) * wv;
            a8[2] += poly_tanh(fmaf((float)(char)(w >> 16), 1.f / SP, phv)) * wv;
            a8[3] += poly_tanh(fmaf((float)(char)(w >> 24), 1.f / SP, phv)) * wv;
            w = uu.y;
            a8[4] += poly_tanh(fmaf((float)(char)(w), 1.f / SP, phv)) * wv;
            a8[5] += poly_tanh(fmaf((float)(char)(w >> 8), 1.f / SP, phv)) * wv;
            a8[6] += poly_tanh(fmaf((float)(char)(w >> 16), 1.f / SP, phv)) * wv;
            a8[7] += poly_tanh(fmaf((float)(char)(w >> 24), 1.f / SP, phv)) * wv;
        }
        for (int j = 0; j < 8; j++) {
            float v = a8[j];
            v += __shfl_xor(v, 16);
            v += __shfl_xor(v, 32);
            a8[j] = v;
        }
        if (lane < 16) {
            for (int j = 0; j < 8; j++) epart[(t0 + j) * 4 + wave] = a8[j];
        }
    }
    __syncthreads();

    // softmax entirely in wave 0 (2 t-values per lane)
    if (wave == 0) {
        int t0 = lane * 2;
        float e0 = epart[t0 * 4] + epart[t0 * 4 + 1] + epart[t0 * 4 + 2] + epart[t0 * 4 + 3];
        float e1 = epart[(t0 + 1) * 4] + epart[(t0 + 1) * 4 + 1] +
                   epart[(t0 + 1) * 4 + 2] + epart[(t0 + 1) * 4 + 3];
        float m = fmaxf(e0, e1);
        for (int o = 32; o >= 1; o >>= 1) m = fmaxf(m, __shfl_xor(m, o));
        float x0 = __expf(e0 - m), x1 = __expf(e1 - m);
        float s = x0 + x1;
        for (int o = 32; o >= 1; o >>= 1) s += __shfl_xor(s, o);
        es_exp[t0] = x0; es_exp[t0 + 1] = x1;
        if (lane == 0) red[0] = 1.f / s;
    }
    __syncthreads();
    float rinv = red[0];

    // context[i] = (sum_t alpha_t * bHf8[b][t][i]) * rinv / SH  (direct L2)
    {
        int cidx = lane, ts = wave;
        float a4[4] = {};
        const char* bb = bHf8 + (size_t)b * 32768 + cidx * 4;
        for (int it = 0; it < 32; it++) {
            int t = it * 4 + ts;
            uint u = *(const uint*)(bb + (size_t)t * 256);
            float al = es_exp[t];
            a4[0] += al * (float)(char)(u);
            a4[1] += al * (float)(char)(u >> 8);
            a4[2] += al * (float)(char)(u >> 16);
            a4[3] += al * (float)(char)(u >> 24);
        }
        for (int j = 0; j < 4; j++) cpart[(cidx * 4 + j) * 4 + ts] = a4[j];
    }
    __syncthreads();
    {
        float sm = cpart[tid * 4 + 0] + cpart[tid * 4 + 1] +
                   cpart[tid * 4 + 2] + cpart[tid * 4 + 3];
        int k = tid;
        int ks = k >> 5, klq = (k >> 3) & 3, j = k & 7;
        XcatS[(size_t)((btile * 16 + ks) * 64 + klq * 16 + blr) * 8 + j] =
            f2bf(sm * rinv * (1.f / SH));
    }
}

// ---------------- per-step LSTM: 128 threads, 2 waves x 2 gate quadrants ----------------
__launch_bounds__(128)
__global__ void lstm_step6(const u16* __restrict__ XcatS, const u16* __restrict__ Wcat3,
                           const float* __restrict__ bsum, const float* __restrict__ WohT,
                           const int* __restrict__ text, float* __restrict__ c_st,
                           u16* __restrict__ hbf_all, char* __restrict__ h8, int step) {
    __shared__ float gq[4 * 64 * 5];   // [q][lane][r] pad-5
    int tid = threadIdx.x;
    int w2 = tid >> 6, lane = tid & 63;
    int lr = lane & 15, lq = lane >> 4;
    int job = blockIdx.x;              // 512 jobs
    int mt = job >> 4, ub = job & 15;
    f32x4 acc0 = {}, acc1 = {};

    for (int ks = 0; ks < 16; ks++) {
        short8 a = *(const short8*)(XcatS + (size_t)((mt * 16 + ks) * 64 + lane) * 8);
        const u16* wb = Wcat3 + (size_t)((ub * 16 + ks) * 4 + w2 * 2) * 512 + lane * 8;
        short8 b0 = *(const short8*)(wb);
        short8 b1 = *(const short8*)(wb + 512);
        acc0 = __builtin_amdgcn_mfma_f32_16x16x32_bf16(a, b0, acc0, 0, 0, 0);
        acc1 = __builtin_amdgcn_mfma_f32_16x16x32_bf16(a, b1, acc1, 0, 0, 0);
    }
    for (int r = 0; r < 4; r++) {
        gq[(w2 * 2) * 320 + lane * 5 + r] = acc0[r];
        gq[(w2 * 2 + 1) * 320 + lane * 5 + r] = acc1[r];
    }
    __syncthreads();

    int u = ub * 16 + lr;
    float bi = bsum[u], bf = bsum[256 + u], bg = bsum[512 + u], bo = bsum[768 + u];
    for (int rr = 0; rr < 2; rr++) {
        int r = w2 * 2 + rr;
        float gi = gq[0 * 320 + lane * 5 + r];
        float gf = gq[1 * 320 + lane * 5 + r];
        float gg = gq[2 * 320 + lane * 5 + r];
        float go = gq[3 * 320 + lane * 5 + r];
        int bgi = mt * 16 + lq * 4 + r;
        int tgt = text[bgi * NSTEP + step];
        const float* wt = WohT + (size_t)tgt * 1024;
        gi += bi + wt[u];
        gf += bf + wt[256 + u];
        gg += bg + wt[512 + u];
        go += bo + wt[768 + u];
        float cold = (step > 0) ? c_st[(size_t)bgi * 256 + u] : 0.f;
        float cn = fast_sig(gf) * cold + fast_sig(gi) * fast_tanh(gg);
        float hn = fast_sig(go) * fast_tanh(cn);
        c_st[(size_t)bgi * 256 + u] = cn;
        hbf_all[(size_t)step * NB * NH + (size_t)bgi * 256 + u] = f2bf(hn);
        h8[(size_t)bgi * 256 + u] = (char)q8i(hn, S8);
    }
}

// ---------------- final logits ----------------
__launch_bounds__(256)
__global__ void gen_logits(const u16* __restrict__ hbf_all, const u16* __restrict__ WgenP,
                           const float* __restrict__ b_gen, float* __restrict__ out) {
    __shared__ u16 As[32 * 32];
    __shared__ u16 Bs[128 * 32];
    int mb = blockIdx.x;
    int tid = threadIdx.x;
    int wave = tid >> 6, lane = tid & 63, lr = lane & 15, lq = lane >> 4;
    int wm = wave >> 1, wn = wave & 1;
    f32x4 acc[4] = {};
    for (int kc = 0; kc < 256; kc += 32) {
        __syncthreads();
        {
            int r = tid >> 3, c4 = (tid & 7) * 4;
            *(ushort4*)(As + r * 32 + c4) =
                *(const ushort4*)(hbf_all + (size_t)(mb * 32 + r) * 256 + kc + c4);
        }
        {
            int r = tid >> 1, h16 = (tid & 1) * 16;
            const u16* src = WgenP + (size_t)r * 256 + kc + h16;
            u16* d = Bs + r * 32 + h16;
            *(ushort4*)(d) = *(const ushort4*)(src);
            *(ushort4*)(d + 4) = *(const ushort4*)(src + 4);
            *(ushort4*)(d + 8) = *(const ushort4*)(src + 8);
            *(ushort4*)(d + 12) = *(const ushort4*)(src + 12);
        }
        __syncthreads();
        short8 a = *reinterpret_cast<const short8*>(As + (wm * 16 + lr) * 32 + lq * 8);
        for (int ni = 0; ni < 4; ni++) {
            short8 bb = *reinterpret_cast<const short8*>(Bs + (wn * 64 + ni * 16 + lr) * 32 + lq * 8);
            acc[ni] = __builtin_amdgcn_mfma_f32_16x16x32_bf16(a, bb, acc[ni], 0, 0, 0);
        }
    }
    for (int ni = 0; ni < 4; ni++) {
        int cidx = wn * 64 + ni * 16 + lr;
        if (cidx >= NCLS) continue;
        float bg = b_gen[cidx];
        int mbase = mb * 32 + wm * 16 + lq * 4;
        for (int r = 0; r < 4; r++) {
            int mm = mbase + r;
            int s = mm >> 9;
            int bb_ = mm & 511;
            float v = (cidx == 3) ? -10000.f : (acc[ni][r] + bg);
            out[(size_t)bb_ * (NSTEP * NCLS) + s * NCLS + cidx] = v;
        }
    }
}

extern "C" void kernel_launch(void* const* d_in, const int* in_sizes, int n_in,
                              void* d_out, int out_size, void* d_ws, size_t ws_size,
                              hipStream_t stream) {
    const float* batch_H = (const float*)d_in[0];
    const int* text = (const int*)d_in[1];
    const float* W_i2h = (const float*)d_in[3];
    const float* W_h2h = (const float*)d_in[4];
    const float* b_h2h = (const float*)d_in[5];
    const float* W_score = (const float*)d_in[6];
    const float* W_ih = (const float*)d_in[7];
    const float* W_hh = (const float*)d_in[8];
    const float* b_ih = (const float*)d_in[9];
    const float* b_hh = (const float*)d_in[10];
    const float* W_gen = (const float*)d_in[11];
    const float* b_gen = (const float*)d_in[12];
    float* out = (float*)d_out;

    char* ws = (char*)d_ws;
    size_t off = 0;
    auto alloc = [&](size_t bytes) {
        void* p = ws + off;
        off += (bytes + 255) & ~(size_t)255;
        return p;
    };
    char* projF8 = (char*)alloc((size_t)16777216);    // [b][h][t] int8
    char* bHf8 = (char*)alloc((size_t)16777216);      // [b][t][i] int8
    char* Wh2h_q8 = (char*)alloc(65536);
    u16* Wi2h_bf = (u16*)alloc(65536 * 2);
    u16* Wcat3 = (u16*)alloc((size_t)524288 * 2);     // frag-swizzled LSTM weights
    float* bsum = (float*)alloc(1024 * 4);
    u16* WgenP = (u16*)alloc(32768 * 2);
    float* WohT = (float*)alloc((size_t)102400 * 4);  // [100][1024]
    u16* XcatS = (u16*)alloc((size_t)262144 * 2);     // A-frag-swizzled LSTM input
    u16* hbf_all = (u16*)alloc((size_t)NSTEP * NB * NH * 2);
    char* h8 = (char*)alloc((size_t)NB * NH);         // h int8 for dot4 ph
    float* c_st = (float*)alloc((size_t)NB * NH * 4);

    prep_weights<<<256, 256, 0, stream>>>(W_h2h, W_i2h, W_ih, W_hh, b_ih, b_hh, W_gen,
                                          Wh2h_q8, Wi2h_bf, Wcat3, bsum, WgenP, WohT);
    gemm_projH5<<<512, 512, 0, stream>>>(batch_H, Wi2h_bf, projF8, bHf8);
    for (int s = 0; s < NSTEP; s++) {
        attn_step6<<<512, 256, 0, stream>>>(hbf_all, h8, Wh2h_q8, b_h2h, W_score,
                                            projF8, bHf8, XcatS, s);
        lstm_step6<<<512, 128, 0, stream>>>(XcatS, Wcat3, bsum, WohT, text, c_st,
                                            hbf_all, h8, s);
    }
    gen_logits<<<416, 256, 0, stream>>>(hbf_all, WgenP, b_gen, out);
}

// Round 8
// 681.794 us; speedup vs baseline: 6.3461x; 1.0916x over previous
//
#include <hip/hip_runtime.h>
#include <hip/hip_fp16.h>
#include <stdint.h>

typedef unsigned short u16;
typedef unsigned char u8;
typedef unsigned int u32;
typedef __attribute__((ext_vector_type(8))) short short8;
typedef __attribute__((ext_vector_type(4))) float f32x4;

#define NSTEP 26
#define NB 512
#define NT 128
#define NH 256
#define NCLS 100

#define SP 32.0f     // proj_H int8 scale
#define SH 24.0f     // batch_H int8 scale
#define SW 2000.0f   // W_h2h int8 scale
#define S8 127.0f    // h int8 scale

#if defined(__has_builtin)
#if __has_builtin(__builtin_amdgcn_sdot4)
#define HAS_SDOT4 1
#endif
#endif

__device__ __forceinline__ u16 f2bf(float f) {
    unsigned u = __float_as_uint(f);
    return (u16)((u + 0x7FFFu + ((u >> 16) & 1u)) >> 16);
}
__device__ __forceinline__ int q8i(float x, float s) {
    float v = fminf(fmaxf(x * s, -127.f), 127.f);
    return __float2int_rn(v);
}
__device__ __forceinline__ float fast_tanh(float x) {
    float e = __expf(2.f * x);
    return 1.f - 2.f / (e + 1.f);
}
__device__ __forceinline__ float fast_sig(float x) { return 1.f / (1.f + __expf(-x)); }
__device__ __forceinline__ void async_g2l(const void* g, void* l) {
    __builtin_amdgcn_global_load_lds((const __attribute__((address_space(1))) u32*)g,
                                     (__attribute__((address_space(3))) u32*)l, 16, 0, 0);
}

// ---------------- tiny: W_i2h f32 -> bf16 (feeds gemm's async B staging) ----------------
__global__ void convW(const float* __restrict__ W_i2h, u16* __restrict__ Wi2h_bf) {
    int idx = blockIdx.x * 256 + threadIdx.x;
    Wi2h_bf[idx] = f2bf(W_i2h[idx]);
}

// ---------------- fused: gemm (blocks<512) + weight prep (blocks>=512) ----------------
__launch_bounds__(512, 3)
__global__ void gemm_fused(const float* __restrict__ bH, const u16* __restrict__ Wi2h_bf,
                           char* __restrict__ projF8, char* __restrict__ bHf8T,
                           const float* __restrict__ W_h2h, const float* __restrict__ W_ih,
                           const float* __restrict__ W_hh, const float* __restrict__ b_ih,
                           const float* __restrict__ b_hh, const float* __restrict__ W_gen,
                           char* __restrict__ Wh2h_q8, u16* __restrict__ Wcat3,
                           float* __restrict__ bsum, u16* __restrict__ WgenP,
                           float* __restrict__ WohT) {
    __shared__ char gsm[49152];
    int tid = threadIdx.x;

    if (blockIdx.x >= 512) {   // ---- prep path: 128 blocks x 512 = 65536 threads ----
        int idx = (blockIdx.x - 512) * 512 + tid;
        if (idx < 65536) Wh2h_q8[idx] = (char)q8i(W_h2h[idx], SW);
        for (int i = idx; i < 16 * 16 * 4 * 64 * 8; i += 65536) {
            int j = i & 7, lane = (i >> 3) & 63, q = (i >> 9) & 3, ks = (i >> 11) & 15, ub = i >> 15;
            int lr = lane & 15, lq = lane >> 4;
            int rg = q * 256 + ub * 16 + lr;
            int k = ks * 32 + lq * 8 + j;
            float v = (k < 256) ? W_ih[(size_t)rg * 356 + k] : W_hh[(size_t)rg * 256 + (k - 256)];
            Wcat3[i] = f2bf(v);
        }
        for (int i = idx; i < 100 * 1024; i += 65536) {
            int t = i >> 10, rg = i & 1023;
            WohT[i] = W_ih[(size_t)rg * 356 + 256 + t];
        }
        if (idx < 1024) bsum[idx] = b_ih[idx] + b_hh[idx];
        if (idx < 32768) {
            int r = idx >> 8, ccol = idx & 255;
            WgenP[idx] = (r < NCLS) ? f2bf(W_gen[r * 256 + ccol]) : (u16)0;
        }
        return;
    }

    // ---- gemm path: 1 batch/block, 128x256, 8 waves 2x4 ----
    u16* As[2] = {(u16*)gsm, (u16*)(gsm + 8192)};
    u16* Bs[2] = {(u16*)(gsm + 16384), (u16*)(gsm + 32768)};
    char* Tt = gsm;   // epilogue transposes: [256 rows][144 pad] int8

    int b = blockIdx.x;
    int wave = tid >> 6, lane = tid & 63, lr = lane & 15, lq = lane >> 4;
    int wm = wave >> 2, wn = wave & 3;
    int ar = tid >> 2, part = tid & 3;
    const float* asrc = bH + ((size_t)b * 128 + ar) * 256 + part * 8;
    f32x4 acc[4][4] = {};
    uint2 bh[8];

    auto stageB = [&](int kc, int buf) {
        for (int i = 0; i < 2; i++) {
            int ch = wave * 2 + i;
            int row = ch * 16 + (lane >> 2);
            const u16* g = Wi2h_bf + (size_t)row * 256 + kc * 32 + (lane & 3) * 8;
            async_g2l(g, (char*)Bs[buf] + ch * 1024 + lane * 16);
        }
    };
    auto writeA = [&](int kc, int buf, float4 v0, float4 v1) {
        u16* dst = As[buf] + ar * 32 + part * 8;
        dst[0] = f2bf(v0.x); dst[1] = f2bf(v0.y); dst[2] = f2bf(v0.z); dst[3] = f2bf(v0.w);
        dst[4] = f2bf(v1.x); dst[5] = f2bf(v1.y); dst[6] = f2bf(v1.z); dst[7] = f2bf(v1.w);
        uint p0 = (uint)(u8)q8i(v0.x, SH) | ((uint)(u8)q8i(v0.y, SH) << 8) |
                  ((uint)(u8)q8i(v0.z, SH) << 16) | ((uint)(u8)q8i(v0.w, SH) << 24);
        uint p1 = (uint)(u8)q8i(v1.x, SH) | ((uint)(u8)q8i(v1.y, SH) << 8) |
                  ((uint)(u8)q8i(v1.z, SH) << 16) | ((uint)(u8)q8i(v1.w, SH) << 24);
        bh[kc].x = p0; bh[kc].y = p1;
    };

    float4 a0 = *(const float4*)(asrc);
    float4 a1 = *(const float4*)(asrc + 4);
    stageB(0, 0);
    writeA(0, 0, a0, a1);
    __syncthreads();

    for (int kc = 0; kc < 8; kc++) {
        int cur = kc & 1, nxt = cur ^ 1;
        if (kc < 7) {
            stageB(kc + 1, nxt);
            a0 = *(const float4*)(asrc + (kc + 1) * 32);
            a1 = *(const float4*)(asrc + (kc + 1) * 32 + 4);
        }
        short8 af[4];
        for (int mi = 0; mi < 4; mi++)
            af[mi] = *(const short8*)(As[cur] + (wm * 64 + mi * 16 + lr) * 32 + lq * 8);
        for (int ni = 0; ni < 4; ni++) {
            short8 bf = *(const short8*)(Bs[cur] + (wn * 64 + ni * 16 + lr) * 32 + lq * 8);
            for (int mi = 0; mi < 4; mi++)
                acc[mi][ni] = __builtin_amdgcn_mfma_f32_16x16x32_bf16(af[mi], bf, acc[mi][ni], 0, 0, 0);
        }
        if (kc < 7) writeA(kc + 1, nxt, a0, a1);
        __syncthreads();   // also protects epilogue Tt aliasing after kc=7
    }

    // epilogue 1: projF8 = transpose(acc) int8
    for (int mi = 0; mi < 4; mi++)
        for (int ni = 0; ni < 4; ni++) {
            int h = wn * 64 + ni * 16 + lr;
            int t = wm * 64 + mi * 16 + lq * 4;
            f32x4 v = acc[mi][ni];
            uint pk = (uint)(u8)q8i(v[0], SP) | ((uint)(u8)q8i(v[1], SP) << 8) |
                      ((uint)(u8)q8i(v[2], SP) << 16) | ((uint)(u8)q8i(v[3], SP) << 24);
            *(uint*)(Tt + h * 144 + t) = pk;
        }
    __syncthreads();
    {
        int hrow = tid >> 1, half = tid & 1;
        const char* src = Tt + hrow * 144 + half * 64;
        char* dst = projF8 + (size_t)b * 32768 + hrow * 128 + half * 64;
        uint4 v0 = *(const uint4*)(src);
        uint4 v1 = *(const uint4*)(src + 16);
        uint4 v2 = *(const uint4*)(src + 32);
        uint4 v3 = *(const uint4*)(src + 48);
        *(uint4*)(dst) = v0; *(uint4*)(dst + 16) = v1;
        *(uint4*)(dst + 32) = v2; *(uint4*)(dst + 48) = v3;
    }
    __syncthreads();

    // epilogue 2: bHf8T[i][t] from bh regs (byte scatter into Tt, then coalesced store)
    {
        for (int kc = 0; kc < 8; kc++) {
            uint wlo = bh[kc].x, whi = bh[kc].y;
            char* t0p = Tt + (size_t)(kc * 32 + part * 8) * 144 + ar;
            t0p[0 * 144] = (char)(wlo);       t0p[1 * 144] = (char)(wlo >> 8);
            t0p[2 * 144] = (char)(wlo >> 16); t0p[3 * 144] = (char)(wlo >> 24);
            t0p[4 * 144] = (char)(whi);       t0p[5 * 144] = (char)(whi >> 8);
            t0p[6 * 144] = (char)(whi >> 16); t0p[7 * 144] = (char)(whi >> 24);
        }
    }
    __syncthreads();
    {
        int irow = tid >> 1, half = tid & 1;
        const char* src = Tt + irow * 144 + half * 64;
        char* dst = bHf8T + (size_t)b * 32768 + irow * 128 + half * 64;
        uint4 v0 = *(const uint4*)(src);
        uint4 v1 = *(const uint4*)(src + 16);
        uint4 v2 = *(const uint4*)(src + 32);
        uint4 v3 = *(const uint4*)(src + 48);
        *(uint4*)(dst) = v0; *(uint4*)(dst + 16) = v1;
        *(uint4*)(dst + 32) = v2; *(uint4*)(dst + 48) = v3;
    }
}

// ---------------- per-step fused attention: 512 threads, half2 tanh ----------------
__launch_bounds__(512)
__global__ void attn_step7(const char* __restrict__ h8, const char* __restrict__ Wh2h_q8,
                           const float* __restrict__ b_h2h, const float* __restrict__ W_score,
                           const char* __restrict__ projF8, const char* __restrict__ bHf8T,
                           u16* __restrict__ XcatS, int step) {
    __shared__ float ph[256];
    __shared__ float ws_s[256];
    __shared__ uint4 h8s[16];
    __shared__ float epart[1024];  // [t 128][wave 8]
    __shared__ float es_exp[128];
    __shared__ float red[4];
    __shared__ float cpx[512];

    int b = blockIdx.x, tid = threadIdx.x;
    int wave = tid >> 6, lane = tid & 63;
    int btile = b >> 4, blr = b & 15;

    if (tid < 16) h8s[tid] = (step > 0) ? ((const uint4*)(h8 + (size_t)b * 256))[tid]
                                        : uint4{0, 0, 0, 0};
    if (tid < 256) {
        ws_s[tid] = W_score[tid];
        if (step == 0) {   // h-half of XcatS = 0 at step 0 (later steps: lstm writes it)
            int k = 256 + tid;
            int ks = k >> 5, klq = (k >> 3) & 3, j = k & 7;
            XcatS[(size_t)((btile * 16 + ks) * 64 + klq * 16 + blr) * 8 + j] = (u16)0;
        }
    }
    __syncthreads();

    // ph[u] = b_h2h[u] + (h8 . Wq8[u,:]) / (SW*S8)
    if (tid < 256) {
        if (step == 0) {
            ph[tid] = b_h2h[tid];
        } else {
            const uint4* wrow = (const uint4*)(Wh2h_q8 + (size_t)tid * 256);
            int acc = 0;
#pragma unroll
            for (int k = 0; k < 16; k++) {
                uint4 w = wrow[k];
                uint4 hh = h8s[k];
#ifdef HAS_SDOT4
                acc = __builtin_amdgcn_sdot4((int)w.x, (int)hh.x, acc, false);
                acc = __builtin_amdgcn_sdot4((int)w.y, (int)hh.y, acc, false);
                acc = __builtin_amdgcn_sdot4((int)w.z, (int)hh.z, acc, false);
                acc = __builtin_amdgcn_sdot4((int)w.w, (int)hh.w, acc, false);
#else
                uint wv[4] = {w.x, w.y, w.z, w.w}, hv[4] = {hh.x, hh.y, hh.z, hh.w};
                for (int c = 0; c < 4; c++)
                    for (int by = 0; by < 32; by += 8)
                        acc += (int)(char)(wv[c] >> by) * (int)(char)(hv[c] >> by);
#endif
            }
            ph[tid] = (float)acc * (1.f / (SW * S8)) + b_h2h[tid];
        }
    }
    __syncthreads();

    // e[t] = sum_h tanh(projF8/SP + ph[h]) * Ws[h]   (half2 poly, 8 hh x 8 t per thread;
    //  clamp done in f32 before packing — ROCm 7.2 lacks __hmax2/__hmin2)
    {
        int tq = tid & 15, hg = tid >> 4;   // hg in [0,32)
        int t0 = tq * 8;
        const __half2 c3 = __float2half2_rn(-0.0016249f), c2 = __float2half2_rn(0.031520f);
        const __half2 c1 = __float2half2_rn(-0.222110f), c0 = __float2half2_rn(0.962117f);
        const float inv = 1.f / SP;
        __half2 acc2[4];
        acc2[0] = __float2half2_rn(0.f); acc2[1] = acc2[0];
        acc2[2] = acc2[0]; acc2[3] = acc2[0];
        const char* base = projF8 + (size_t)b * 32768 + t0;
#pragma unroll
        for (int hh = 0; hh < 8; hh++) {
            int R = hg * 8 + hh;
            uint2 uu = *(const uint2*)(base + R * 128);
            float phv = ph[R];
            __half2 wv2 = __float2half2_rn(ws_s[R]);
            uint wpair[2] = {uu.x, uu.y};
#pragma unroll
            for (int half_i = 0; half_i < 2; half_i++) {
                uint w = wpair[half_i];
#pragma unroll
                for (int pp = 0; pp < 2; pp++) {
                    float xa = fmaf((float)(char)(w >> (pp * 16)), inv, phv);
                    float xb = fmaf((float)(char)(w >> (pp * 16 + 8)), inv, phv);
                    xa = fminf(fmaxf(xa, -3.0f), 3.0f);
                    xb = fminf(fmaxf(xb, -3.0f), 3.0f);
                    __half2 x = __floats2half2_rn(xa, xb);
                    __half2 u2 = __hmul2(x, x);
                    __half2 p = __hfma2(__hfma2(__hfma2(c3, u2, c2), u2, c1), u2, c0);
                    acc2[half_i * 2 + pp] = __hfma2(__hmul2(x, p), wv2, acc2[half_i * 2 + pp]);
                }
            }
        }
        float a8[8];
#pragma unroll
        for (int q = 0; q < 4; q++) {
            a8[q * 2] = __low2float(acc2[q]);
            a8[q * 2 + 1] = __high2float(acc2[q]);
        }
#pragma unroll
        for (int j = 0; j < 8; j++) {
            float v = a8[j];
            v += __shfl_xor(v, 16);
            v += __shfl_xor(v, 32);
            a8[j] = v;
        }
        if (lane < 16) {
#pragma unroll
            for (int j = 0; j < 8; j++) epart[(t0 + j) * 8 + wave] = a8[j];
        }
    }
    __syncthreads();

    // softmax in wave 0
    if (wave == 0) {
        int t0 = lane * 2;
        float e0 = 0.f, e1 = 0.f;
#pragma unroll
        for (int w = 0; w < 8; w++) {
            e0 += epart[t0 * 8 + w];
            e1 += epart[(t0 + 1) * 8 + w];
        }
        float m = fmaxf(e0, e1);
        for (int o = 32; o >= 1; o >>= 1) m = fmaxf(m, __shfl_xor(m, o));
        float x0 = __expf(e0 - m), x1 = __expf(e1 - m);
        float s = x0 + x1;
        for (int o = 32; o >= 1; o >>= 1) s += __shfl_xor(s, o);
        es_exp[t0] = x0; es_exp[t0 + 1] = x1;
        if (lane == 0) red[0] = 1.f / s;
    }
    __syncthreads();
    float rinv = red[0];

    // context[i] = sum_t alpha_t * bHf8T[i][t]  (coalesced uint4 row reads)
    {
        int i = tid >> 1, th = tid & 1;
        const char* src = bHf8T + (size_t)b * 32768 + i * 128 + th * 64;
        float a = 0.f;
#pragma unroll
        for (int q = 0; q < 4; q++) {
            uint4 u = ((const uint4*)src)[q];
            uint wv[4] = {u.x, u.y, u.z, u.w};
#pragma unroll
            for (int c = 0; c < 4; c++) {
                uint w = wv[c];
                int tb = th * 64 + q * 16 + c * 4;
                a += es_exp[tb + 0] * (float)(char)(w);
                a += es_exp[tb + 1] * (float)(char)(w >> 8);
                a += es_exp[tb + 2] * (float)(char)(w >> 16);
                a += es_exp[tb + 3] * (float)(char)(w >> 24);
            }
        }
        cpx[tid] = a;
    }
    __syncthreads();
    if (tid < 256) {
        float sm = cpx[tid * 2] + cpx[tid * 2 + 1];
        int k = tid, ks = k >> 5, klq = (k >> 3) & 3, j = k & 7;
        XcatS[(size_t)((btile * 16 + ks) * 64 + klq * 16 + blr) * 8 + j] =
            f2bf(sm * rinv * (1.f / SH));
    }
}

// ---------------- per-step LSTM: also writes XcatS h-half + h8 ----------------
__launch_bounds__(128)
__global__ void lstm_step7(const u16* __restrict__ XcatS_c, const u16* __restrict__ Wcat3,
                           const float* __restrict__ bsum, const float* __restrict__ WohT,
                           const int* __restrict__ text, float* __restrict__ c_st,
                           u16* __restrict__ hbf_all, char* __restrict__ h8,
                           u16* __restrict__ XcatS, int step) {
    __shared__ float gq[4 * 64 * 5];
    int tid = threadIdx.x;
    int w2 = tid >> 6, lane = tid & 63;
    int lr = lane & 15, lq = lane >> 4;
    int job = blockIdx.x;
    int mt = job >> 4, ub = job & 15;
    f32x4 acc0 = {}, acc1 = {};

    for (int ks = 0; ks < 16; ks++) {
        short8 a = *(const short8*)(XcatS_c + (size_t)((mt * 16 + ks) * 64 + lane) * 8);
        const u16* wb = Wcat3 + (size_t)((ub * 16 + ks) * 4 + w2 * 2) * 512 + lane * 8;
        short8 b0 = *(const short8*)(wb);
        short8 b1 = *(const short8*)(wb + 512);
        acc0 = __builtin_amdgcn_mfma_f32_16x16x32_bf16(a, b0, acc0, 0, 0, 0);
        acc1 = __builtin_amdgcn_mfma_f32_16x16x32_bf16(a, b1, acc1, 0, 0, 0);
    }
    for (int r = 0; r < 4; r++) {
        gq[(w2 * 2) * 320 + lane * 5 + r] = acc0[r];
        gq[(w2 * 2 + 1) * 320 + lane * 5 + r] = acc1[r];
    }
    __syncthreads();

    int u = ub * 16 + lr;
    float bi = bsum[u], bf = bsum[256 + u], bg = bsum[512 + u], bo = bsum[768 + u];
    for (int rr = 0; rr < 2; rr++) {
        int r = w2 * 2 + rr;
        float gi = gq[0 * 320 + lane * 5 + r];
        float gf = gq[1 * 320 + lane * 5 + r];
        float gg = gq[2 * 320 + lane * 5 + r];
        float go = gq[3 * 320 + lane * 5 + r];
        int bgi = mt * 16 + lq * 4 + r;
        int tgt = text[bgi * NSTEP + step];
        const float* wt = WohT + (size_t)tgt * 1024;
        gi += bi + wt[u];
        gf += bf + wt[256 + u];
        gg += bg + wt[512 + u];
        go += bo + wt[768 + u];
        float cold = (step > 0) ? c_st[(size_t)bgi * 256 + u] : 0.f;
        float cn = fast_sig(gf) * cold + fast_sig(gi) * fast_tanh(gg);
        float hn = fast_sig(go) * fast_tanh(cn);
        c_st[(size_t)bgi * 256 + u] = cn;
        hbf_all[(size_t)step * NB * NH + (size_t)bgi * 256 + u] = f2bf(hn);
        h8[(size_t)bgi * 256 + u] = (char)q8i(hn, S8);
        {   // XcatS h-half for next step: k = 256+u, batch bgi
            int ks2 = 8 + (u >> 5), klq = (u >> 3) & 3, j = u & 7;
            int btile = bgi >> 4, blr2 = bgi & 15;
            XcatS[(size_t)((btile * 16 + ks2) * 64 + klq * 16 + blr2) * 8 + j] = f2bf(hn);
        }
    }
}

// ---------------- final logits ----------------
__launch_bounds__(256)
__global__ void gen_logits(const u16* __restrict__ hbf_all, const u16* __restrict__ WgenP,
                           const float* __restrict__ b_gen, float* __restrict__ out) {
    __shared__ u16 As[32 * 32];
    __shared__ u16 Bs[128 * 32];
    int mb = blockIdx.x;
    int tid = threadIdx.x;
    int wave = tid >> 6, lane = tid & 63, lr = lane & 15, lq = lane >> 4;
    int wm = wave >> 1, wn = wave & 1;
    f32x4 acc[4] = {};
    for (int kc = 0; kc < 256; kc += 32) {
        __syncthreads();
        {
            int r = tid >> 3, c4 = (tid & 7) * 4;
            *(ushort4*)(As + r * 32 + c4) =
                *(const ushort4*)(hbf_all + (size_t)(mb * 32 + r) * 256 + kc + c4);
        }
        {
            int r = tid >> 1, h16 = (tid & 1) * 16;
            const u16* src = WgenP + (size_t)r * 256 + kc + h16;
            u16* d = Bs + r * 32 + h16;
            *(ushort4*)(d) = *(const ushort4*)(src);
            *(ushort4*)(d + 4) = *(const ushort4*)(src + 4);
            *(ushort4*)(d + 8) = *(const ushort4*)(src + 8);
            *(ushort4*)(d + 12) = *(const ushort4*)(src + 12);
        }
        __syncthreads();
        short8 a = *reinterpret_cast<const short8*>(As + (wm * 16 + lr) * 32 + lq * 8);
        for (int ni = 0; ni < 4; ni++) {
            short8 bb = *reinterpret_cast<const short8*>(Bs + (wn * 64 + ni * 16 + lr) * 32 + lq * 8);
            acc[ni] = __builtin_amdgcn_mfma_f32_16x16x32_bf16(a, bb, acc[ni], 0, 0, 0);
        }
    }
    for (int ni = 0; ni < 4; ni++) {
        int cidx = wn * 64 + ni * 16 + lr;
        if (cidx >= NCLS) continue;
        float bg = b_gen[cidx];
        int mbase = mb * 32 + wm * 16 + lq * 4;
        for (int r = 0; r < 4; r++) {
            int mm = mbase + r;
            int s = mm >> 9;
            int bb_ = mm & 511;
            float v = (cidx == 3) ? -10000.f : (acc[ni][r] + bg);
            out[(size_t)bb_ * (NSTEP * NCLS) + s * NCLS + cidx] = v;
        }
    }
}

extern "C" void kernel_launch(void* const* d_in, const int* in_sizes, int n_in,
                              void* d_out, int out_size, void* d_ws, size_t ws_size,
                              hipStream_t stream) {
    const float* batch_H = (const float*)d_in[0];
    const int* text = (const int*)d_in[1];
    const float* W_i2h = (const float*)d_in[3];
    const float* W_h2h = (const float*)d_in[4];
    const float* b_h2h = (const float*)d_in[5];
    const float* W_score = (const float*)d_in[6];
    const float* W_ih = (const float*)d_in[7];
    const float* W_hh = (const float*)d_in[8];
    const float* b_ih = (const float*)d_in[9];
    const float* b_hh = (const float*)d_in[10];
    const float* W_gen = (const float*)d_in[11];
    const float* b_gen = (const float*)d_in[12];
    float* out = (float*)d_out;

    char* ws = (char*)d_ws;
    size_t off = 0;
    auto alloc = [&](size_t bytes) {
        void* p = ws + off;
        off += (bytes + 255) & ~(size_t)255;
        return p;
    };
    char* projF8 = (char*)alloc((size_t)16777216);    // [b][h][t] int8
    char* bHf8T = (char*)alloc((size_t)16777216);     // [b][i][t] int8 (transposed)
    char* Wh2h_q8 = (char*)alloc(65536);
    u16* Wi2h_bf = (u16*)alloc(65536 * 2);
    u16* Wcat3 = (u16*)alloc((size_t)524288 * 2);     // frag-swizzled LSTM weights
    float* bsum = (float*)alloc(1024 * 4);
    u16* WgenP = (u16*)alloc(32768 * 2);
    float* WohT = (float*)alloc((size_t)102400 * 4);  // [100][1024]
    u16* XcatS = (u16*)alloc((size_t)262144 * 2);     // A-frag-swizzled LSTM input
    u16* hbf_all = (u16*)alloc((size_t)NSTEP * NB * NH * 2);
    char* h8 = (char*)alloc((size_t)NB * NH);
    float* c_st = (float*)alloc((size_t)NB * NH * 4);

    convW<<<256, 256, 0, stream>>>(W_i2h, Wi2h_bf);
    gemm_fused<<<640, 512, 0, stream>>>(batch_H, Wi2h_bf, projF8, bHf8T,
                                        W_h2h, W_ih, W_hh, b_ih, b_hh, W_gen,
                                        Wh2h_q8, Wcat3, bsum, WgenP, WohT);
    for (int s = 0; s < NSTEP; s++) {
        attn_step7<<<512, 512, 0, stream>>>(h8, Wh2h_q8, b_h2h, W_score,
                                            projF8, bHf8T, XcatS, s);
        lstm_step7<<<512, 128, 0, stream>>>(XcatS, Wcat3, bsum, WohT, text, c_st,
                                            hbf_all, h8, XcatS, s);
    }
    gen_logits<<<416, 256, 0, stream>>>(hbf_all, WgenP, b_gen, out);
}

// Round 9
// 680.263 us; speedup vs baseline: 6.3604x; 1.0023x over previous
//
#include <hip/hip_runtime.h>
#include <hip/hip_fp16.h>
#include <stdint.h>

typedef unsigned short u16;
typedef unsigned char u8;
typedef unsigned int u32;
typedef __attribute__((ext_vector_type(8))) short short8;
typedef __attribute__((ext_vector_type(4))) float f32x4;

#define NSTEP 26
#define NB 512
#define NT 128
#define NH 256
#define NCLS 100

#define SP 32.0f     // proj_H int8 scale
#define SH 24.0f     // batch_H int8 scale
#define SW 2000.0f   // W_h2h int8 scale
#define S8 127.0f    // h int8 scale

#if defined(__has_builtin)
#if __has_builtin(__builtin_amdgcn_sdot4)
#define HAS_SDOT4 1
#endif
#endif

__device__ __forceinline__ u16 f2bf(float f) {
    unsigned u = __float_as_uint(f);
    return (u16)((u + 0x7FFFu + ((u >> 16) & 1u)) >> 16);
}
__device__ __forceinline__ int q8i(float x, float s) {
    float v = fminf(fmaxf(x * s, -127.f), 127.f);
    return __float2int_rn(v);
}
__device__ __forceinline__ float fast_tanh(float x) {
    float e = __expf(2.f * x);
    return 1.f - 2.f / (e + 1.f);
}
__device__ __forceinline__ float fast_sig(float x) { return 1.f / (1.f + __expf(-x)); }
__device__ __forceinline__ void async_g2l(const void* g, void* l) {
    __builtin_amdgcn_global_load_lds((const __attribute__((address_space(1))) u32*)g,
                                     (__attribute__((address_space(3))) u32*)l, 16, 0, 0);
}

// ---------------- prep: ALL weight conversions + XcatS h-half zero ----------------
__global__ void prep_all(const float* __restrict__ W_h2h, const float* __restrict__ W_i2h,
                         const float* __restrict__ W_ih, const float* __restrict__ W_hh,
                         const float* __restrict__ b_ih, const float* __restrict__ b_hh,
                         const float* __restrict__ W_gen,
                         char* __restrict__ Wh2h_q8, u16* __restrict__ Wi2h_bf,
                         u16* __restrict__ Wcat3, float* __restrict__ bsum,
                         u16* __restrict__ WgenP, float* __restrict__ WohT,
                         u16* __restrict__ XcatS) {
    int idx = blockIdx.x * 256 + threadIdx.x;  // 65536 threads
    if (idx < 65536) {
        Wh2h_q8[idx] = (char)q8i(W_h2h[idx], SW);
        Wi2h_bf[idx] = f2bf(W_i2h[idx]);
    }
    for (int i = idx; i < 16 * 16 * 4 * 64 * 8; i += 65536) {
        int j = i & 7, lane = (i >> 3) & 63, q = (i >> 9) & 3, ks = (i >> 11) & 15, ub = i >> 15;
        int lr = lane & 15, lq = lane >> 4;
        int rg = q * 256 + ub * 16 + lr;
        int k = ks * 32 + lq * 8 + j;
        float v = (k < 256) ? W_ih[(size_t)rg * 356 + k] : W_hh[(size_t)rg * 256 + (k - 256)];
        Wcat3[i] = f2bf(v);
    }
    for (int i = idx; i < 100 * 1024; i += 65536) {
        int t = i >> 10, rg = i & 1023;
        WohT[i] = W_ih[(size_t)rg * 356 + 256 + t];
    }
    if (idx < 1024) bsum[idx] = b_ih[idx] + b_hh[idx];
    if (idx < 32768) {
        int r = idx >> 8, ccol = idx & 255;
        WgenP[idx] = (r < NCLS) ? f2bf(W_gen[r * 256 + ccol]) : (u16)0;
    }
    // zero the h-half of XcatS (k in [256,512)) for step 0: that is ks in [8,16)
    // XcatS layout: [(btile*16+ks)*64 + lane]*8 + j, btile<32, ks<16
    for (int i = idx; i < 32 * 8 * 64 * 8; i += 65536) {
        int j = i & 7, lane = (i >> 3) & 63, ks = 8 + ((i >> 9) & 7), btile = i >> 12;
        XcatS[(size_t)((btile * 16 + ks) * 64 + lane) * 8 + j] = (u16)0;
    }
}

// ---------------- proj_H GEMM: 1 batch/block, 128x256, 8 waves 2x4 (R6-proven) --------
__launch_bounds__(512, 3)
__global__ void gemm_projH5(const float* __restrict__ bH, const u16* __restrict__ Wi2h_bf,
                            char* __restrict__ projF8, char* __restrict__ bHf8T) {
    __shared__ char gsm[49152];
    u16* As[2] = {(u16*)gsm, (u16*)(gsm + 8192)};
    u16* Bs[2] = {(u16*)(gsm + 16384), (u16*)(gsm + 32768)};
    char* Tt = gsm;   // epilogue: [256 rows][144 pad] int8 (aliases As after final sync)

    int b = blockIdx.x, tid = threadIdx.x;
    int wave = tid >> 6, lane = tid & 63, lr = lane & 15, lq = lane >> 4;
    int wm = wave >> 2, wn = wave & 3;
    int ar = tid >> 2, part = tid & 3;
    const float* asrc = bH + ((size_t)b * 128 + ar) * 256 + part * 8;
    f32x4 acc[4][4] = {};
    uint2 bh[8];

    auto stageB = [&](int kc, int buf) {
        for (int i = 0; i < 2; i++) {
            int ch = wave * 2 + i;
            int row = ch * 16 + (lane >> 2);
            const u16* g = Wi2h_bf + (size_t)row * 256 + kc * 32 + (lane & 3) * 8;
            async_g2l(g, (char*)Bs[buf] + ch * 1024 + lane * 16);
        }
    };
    auto writeA = [&](int kc, int buf, float4 v0, float4 v1) {
        u16* dst = As[buf] + ar * 32 + part * 8;
        dst[0] = f2bf(v0.x); dst[1] = f2bf(v0.y); dst[2] = f2bf(v0.z); dst[3] = f2bf(v0.w);
        dst[4] = f2bf(v1.x); dst[5] = f2bf(v1.y); dst[6] = f2bf(v1.z); dst[7] = f2bf(v1.w);
        uint p0 = (uint)(u8)q8i(v0.x, SH) | ((uint)(u8)q8i(v0.y, SH) << 8) |
                  ((uint)(u8)q8i(v0.z, SH) << 16) | ((uint)(u8)q8i(v0.w, SH) << 24);
        uint p1 = (uint)(u8)q8i(v1.x, SH) | ((uint)(u8)q8i(v1.y, SH) << 8) |
                  ((uint)(u8)q8i(v1.z, SH) << 16) | ((uint)(u8)q8i(v1.w, SH) << 24);
        bh[kc].x = p0; bh[kc].y = p1;
    };

    float4 a0 = *(const float4*)(asrc);
    float4 a1 = *(const float4*)(asrc + 4);
    stageB(0, 0);
    writeA(0, 0, a0, a1);
    __syncthreads();

    for (int kc = 0; kc < 8; kc++) {
        int cur = kc & 1, nxt = cur ^ 1;
        if (kc < 7) {
            stageB(kc + 1, nxt);
            a0 = *(const float4*)(asrc + (kc + 1) * 32);
            a1 = *(const float4*)(asrc + (kc + 1) * 32 + 4);
        }
        short8 af[4];
        for (int mi = 0; mi < 4; mi++)
            af[mi] = *(const short8*)(As[cur] + (wm * 64 + mi * 16 + lr) * 32 + lq * 8);
        for (int ni = 0; ni < 4; ni++) {
            short8 bf = *(const short8*)(Bs[cur] + (wn * 64 + ni * 16 + lr) * 32 + lq * 8);
            for (int mi = 0; mi < 4; mi++)
                acc[mi][ni] = __builtin_amdgcn_mfma_f32_16x16x32_bf16(af[mi], bf, acc[mi][ni], 0, 0, 0);
        }
        if (kc < 7) writeA(kc + 1, nxt, a0, a1);
        __syncthreads();
    }

    // flush bHf8T: epilogue 2 below transposes via LDS; first projF8 transpose
    for (int mi = 0; mi < 4; mi++)
        for (int ni = 0; ni < 4; ni++) {
            int h = wn * 64 + ni * 16 + lr;
            int t = wm * 64 + mi * 16 + lq * 4;
            f32x4 v = acc[mi][ni];
            uint pk = (uint)(u8)q8i(v[0], SP) | ((uint)(u8)q8i(v[1], SP) << 8) |
                      ((uint)(u8)q8i(v[2], SP) << 16) | ((uint)(u8)q8i(v[3], SP) << 24);
            *(uint*)(Tt + h * 144 + t) = pk;
        }
    __syncthreads();
    {
        int hrow = tid >> 1, half = tid & 1;
        const char* src = Tt + hrow * 144 + half * 64;
        char* dst = projF8 + (size_t)b * 32768 + hrow * 128 + half * 64;
        uint4 v0 = *(const uint4*)(src);
        uint4 v1 = *(const uint4*)(src + 16);
        uint4 v2 = *(const uint4*)(src + 32);
        uint4 v3 = *(const uint4*)(src + 48);
        *(uint4*)(dst) = v0; *(uint4*)(dst + 16) = v1;
        *(uint4*)(dst + 32) = v2; *(uint4*)(dst + 48) = v3;
    }
    __syncthreads();
    {
        for (int kc = 0; kc < 8; kc++) {
            uint wlo = bh[kc].x, whi = bh[kc].y;
            char* t0p = Tt + (size_t)(kc * 32 + part * 8) * 144 + ar;
            t0p[0 * 144] = (char)(wlo);       t0p[1 * 144] = (char)(wlo >> 8);
            t0p[2 * 144] = (char)(wlo >> 16); t0p[3 * 144] = (char)(wlo >> 24);
            t0p[4 * 144] = (char)(whi);       t0p[5 * 144] = (char)(whi >> 8);
            t0p[6 * 144] = (char)(whi >> 16); t0p[7 * 144] = (char)(whi >> 24);
        }
    }
    __syncthreads();
    {
        int irow = tid >> 1, half = tid & 1;
        const char* src = Tt + irow * 144 + half * 64;
        char* dst = bHf8T + (size_t)b * 32768 + irow * 128 + half * 64;
        uint4 v0 = *(const uint4*)(src);
        uint4 v1 = *(const uint4*)(src + 16);
        uint4 v2 = *(const uint4*)(src + 32);
        uint4 v3 = *(const uint4*)(src + 48);
        *(uint4*)(dst) = v0; *(uint4*)(dst + 16) = v1;
        *(uint4*)(dst + 32) = v2; *(uint4*)(dst + 48) = v3;
    }
}

// ---------------- per-step fused attention: 512 threads, uint4 e-loop ----------------
__launch_bounds__(512)
__global__ void attn_step8(const char* __restrict__ h8, const char* __restrict__ Wh2h_q8,
                           const float* __restrict__ b_h2h, const float* __restrict__ W_score,
                           const char* __restrict__ projF8, const char* __restrict__ bHf8T,
                           u16* __restrict__ XcatS, int step) {
    __shared__ float ph[256];
    __shared__ float ws_s[256];
    __shared__ uint4 h8s[16];
    __shared__ float epart[1024];  // [t 128][wave 8]
    __shared__ float es_exp[128];
    __shared__ float red[4];
    __shared__ float cpx[512];

    int b = blockIdx.x, tid = threadIdx.x;
    int wave = tid >> 6, lane = tid & 63;
    int btile = b >> 4, blr = b & 15;

    if (tid < 16) h8s[tid] = (step > 0) ? ((const uint4*)(h8 + (size_t)b * 256))[tid]
                                        : uint4{0, 0, 0, 0};
    if (tid < 256) ws_s[tid] = W_score[tid];
    __syncthreads();

    // ph[u] = b_h2h[u] + (h8 . Wq8[u,:]) / (SW*S8)
    if (tid < 256) {
        if (step == 0) {
            ph[tid] = b_h2h[tid];
        } else {
            const uint4* wrow = (const uint4*)(Wh2h_q8 + (size_t)tid * 256);
            int acc = 0;
#pragma unroll
            for (int k = 0; k < 16; k++) {
                uint4 w = wrow[k];
                uint4 hh = h8s[k];
#ifdef HAS_SDOT4
                acc = __builtin_amdgcn_sdot4((int)w.x, (int)hh.x, acc, false);
                acc = __builtin_amdgcn_sdot4((int)w.y, (int)hh.y, acc, false);
                acc = __builtin_amdgcn_sdot4((int)w.z, (int)hh.z, acc, false);
                acc = __builtin_amdgcn_sdot4((int)w.w, (int)hh.w, acc, false);
#else
                uint wv[4] = {w.x, w.y, w.z, w.w}, hv[4] = {hh.x, hh.y, hh.z, hh.w};
                for (int c = 0; c < 4; c++)
                    for (int by = 0; by < 32; by += 8)
                        acc += (int)(char)(wv[c] >> by) * (int)(char)(hv[c] >> by);
#endif
            }
            ph[tid] = (float)acc * (1.f / (SW * S8)) + b_h2h[tid];
        }
    }
    __syncthreads();

    // e[t] = sum_h tanh(projF8/SP + ph[h]) * Ws[h]
    // thread: tq=tid&7 -> 16 t values; hg=tid>>3 -> 4 h rows. uint4 loads (16 t each).
    {
        int tq = tid & 7, hg = tid >> 3;   // hg in [0,64)
        int t0 = tq * 16;
        const __half2 c3 = __float2half2_rn(-0.0016249f), c2 = __float2half2_rn(0.031520f);
        const __half2 c1 = __float2half2_rn(-0.222110f), c0 = __float2half2_rn(0.962117f);
        const float inv = 1.f / SP;
        __half2 acc2[8];
#pragma unroll
        for (int q = 0; q < 8; q++) acc2[q] = __float2half2_rn(0.f);
        const char* base = projF8 + (size_t)b * 32768 + t0;
#pragma unroll
        for (int hh = 0; hh < 4; hh++) {
            int R = hg * 4 + hh;
            uint4 uu = *(const uint4*)(base + R * 128);
            float phv = ph[R];
            __half2 wv2 = __float2half2_rn(ws_s[R]);
            uint wq[4] = {uu.x, uu.y, uu.z, uu.w};
#pragma unroll
            for (int wi = 0; wi < 4; wi++) {
                uint w = wq[wi];
#pragma unroll
                for (int pp = 0; pp < 2; pp++) {
                    float xa = fmaf((float)(char)(w >> (pp * 16)), inv, phv);
                    float xb = fmaf((float)(char)(w >> (pp * 16 + 8)), inv, phv);
                    xa = fminf(fmaxf(xa, -3.0f), 3.0f);
                    xb = fminf(fmaxf(xb, -3.0f), 3.0f);
                    __half2 x = __floats2half2_rn(xa, xb);
                    __half2 u2 = __hmul2(x, x);
                    __half2 p = __hfma2(__hfma2(__hfma2(c3, u2, c2), u2, c1), u2, c0);
                    acc2[wi * 2 + pp] = __hfma2(__hmul2(x, p), wv2, acc2[wi * 2 + pp]);
                }
            }
        }
        float a16[16];
#pragma unroll
        for (int q = 0; q < 8; q++) {
            a16[q * 2] = __low2float(acc2[q]);
            a16[q * 2 + 1] = __high2float(acc2[q]);
        }
#pragma unroll
        for (int j = 0; j < 16; j++) {
            float v = a16[j];
            v += __shfl_xor(v, 8);
            v += __shfl_xor(v, 16);
            v += __shfl_xor(v, 32);
            a16[j] = v;
        }
        if (lane < 8) {
#pragma unroll
            for (int j = 0; j < 16; j++) epart[(t0 + j) * 8 + wave] = a16[j];
        }
    }
    __syncthreads();

    // softmax in wave 0
    if (wave == 0) {
        int t0 = lane * 2;
        float e0 = 0.f, e1 = 0.f;
#pragma unroll
        for (int w = 0; w < 8; w++) {
            e0 += epart[t0 * 8 + w];
            e1 += epart[(t0 + 1) * 8 + w];
        }
        float m = fmaxf(e0, e1);
        for (int o = 32; o >= 1; o >>= 1) m = fmaxf(m, __shfl_xor(m, o));
        float x0 = __expf(e0 - m), x1 = __expf(e1 - m);
        float s = x0 + x1;
        for (int o = 32; o >= 1; o >>= 1) s += __shfl_xor(s, o);
        es_exp[t0] = x0; es_exp[t0 + 1] = x1;
        if (lane == 0) red[0] = 1.f / s;
    }
    __syncthreads();
    float rinv = red[0];

    // context[i] = sum_t alpha_t * bHf8T[i][t]
    {
        int i = tid >> 1, th = tid & 1;
        const char* src = bHf8T + (size_t)b * 32768 + i * 128 + th * 64;
        float a = 0.f;
#pragma unroll
        for (int q = 0; q < 4; q++) {
            uint4 u = ((const uint4*)src)[q];
            uint wv[4] = {u.x, u.y, u.z, u.w};
#pragma unroll
            for (int c = 0; c < 4; c++) {
                uint w = wv[c];
                int tb = th * 64 + q * 16 + c * 4;
                a += es_exp[tb + 0] * (float)(char)(w);
                a += es_exp[tb + 1] * (float)(char)(w >> 8);
                a += es_exp[tb + 2] * (float)(char)(w >> 16);
                a += es_exp[tb + 3] * (float)(char)(w >> 24);
            }
        }
        cpx[tid] = a;
    }
    __syncthreads();
    if (tid < 256) {
        float sm = cpx[tid * 2] + cpx[tid * 2 + 1];
        int k = tid, ks = k >> 5, klq = (k >> 3) & 3, j = k & 7;
        XcatS[(size_t)((btile * 16 + ks) * 64 + klq * 16 + blr) * 8 + j] =
            f2bf(sm * rinv * (1.f / SH));
    }
}

// ---------------- per-step LSTM: also writes XcatS h-half + h8 ----------------
__launch_bounds__(128)
__global__ void lstm_step7(const u16* __restrict__ XcatS_c, const u16* __restrict__ Wcat3,
                           const float* __restrict__ bsum, const float* __restrict__ WohT,
                           const int* __restrict__ text, float* __restrict__ c_st,
                           u16* __restrict__ hbf_all, char* __restrict__ h8,
                           u16* __restrict__ XcatS, int step) {
    __shared__ float gq[4 * 64 * 5];
    int tid = threadIdx.x;
    int w2 = tid >> 6, lane = tid & 63;
    int lr = lane & 15, lq = lane >> 4;
    int job = blockIdx.x;
    int mt = job >> 4, ub = job & 15;
    f32x4 acc0 = {}, acc1 = {};

    for (int ks = 0; ks < 16; ks++) {
        short8 a = *(const short8*)(XcatS_c + (size_t)((mt * 16 + ks) * 64 + lane) * 8);
        const u16* wb = Wcat3 + (size_t)((ub * 16 + ks) * 4 + w2 * 2) * 512 + lane * 8;
        short8 b0 = *(const short8*)(wb);
        short8 b1 = *(const short8*)(wb + 512);
        acc0 = __builtin_amdgcn_mfma_f32_16x16x32_bf16(a, b0, acc0, 0, 0, 0);
        acc1 = __builtin_amdgcn_mfma_f32_16x16x32_bf16(a, b1, acc1, 0, 0, 0);
    }
    for (int r = 0; r < 4; r++) {
        gq[(w2 * 2) * 320 + lane * 5 + r] = acc0[r];
        gq[(w2 * 2 + 1) * 320 + lane * 5 + r] = acc1[r];
    }
    __syncthreads();

    int u = ub * 16 + lr;
    float bi = bsum[u], bf = bsum[256 + u], bg = bsum[512 + u], bo = bsum[768 + u];
    for (int rr = 0; rr < 2; rr++) {
        int r = w2 * 2 + rr;
        float gi = gq[0 * 320 + lane * 5 + r];
        float gf = gq[1 * 320 + lane * 5 + r];
        float gg = gq[2 * 320 + lane * 5 + r];
        float go = gq[3 * 320 + lane * 5 + r];
        int bgi = mt * 16 + lq * 4 + r;
        int tgt = text[bgi * NSTEP + step];
        const float* wt = WohT + (size_t)tgt * 1024;
        gi += bi + wt[u];
        gf += bf + wt[256 + u];
        gg += bg + wt[512 + u];
        go += bo + wt[768 + u];
        float cold = (step > 0) ? c_st[(size_t)bgi * 256 + u] : 0.f;
        float cn = fast_sig(gf) * cold + fast_sig(gi) * fast_tanh(gg);
        float hn = fast_sig(go) * fast_tanh(cn);
        c_st[(size_t)bgi * 256 + u] = cn;
        hbf_all[(size_t)step * NB * NH + (size_t)bgi * 256 + u] = f2bf(hn);
        h8[(size_t)bgi * 256 + u] = (char)q8i(hn, S8);
        {   // XcatS h-half for next step: k = 256+u, batch bgi
            int ks2 = 8 + (u >> 5), klq = (u >> 3) & 3, j = u & 7;
            int btile = bgi >> 4, blr2 = bgi & 15;
            XcatS[(size_t)((btile * 16 + ks2) * 64 + klq * 16 + blr2) * 8 + j] = f2bf(hn);
        }
    }
}

// ---------------- final logits ----------------
__launch_bounds__(256)
__global__ void gen_logits(const u16* __restrict__ hbf_all, const u16* __restrict__ WgenP,
                           const float* __restrict__ b_gen, float* __restrict__ out) {
    __shared__ u16 As[32 * 32];
    __shared__ u16 Bs[128 * 32];
    int mb = blockIdx.x;
    int tid = threadIdx.x;
    int wave = tid >> 6, lane = tid & 63, lr = lane & 15, lq = lane >> 4;
    int wm = wave >> 1, wn = wave & 1;
    f32x4 acc[4] = {};
    for (int kc = 0; kc < 256; kc += 32) {
        __syncthreads();
        {
            int r = tid >> 3, c4 = (tid & 7) * 4;
            *(ushort4*)(As + r * 32 + c4) =
                *(const ushort4*)(hbf_all + (size_t)(mb * 32 + r) * 256 + kc + c4);
        }
        {
            int r = tid >> 1, h16 = (tid & 1) * 16;
            const u16* src = WgenP + (size_t)r * 256 + kc + h16;
            u16* d = Bs + r * 32 + h16;
            *(ushort4*)(d) = *(const ushort4*)(src);
            *(ushort4*)(d + 4) = *(const ushort4*)(src + 4);
            *(ushort4*)(d + 8) = *(const ushort4*)(src + 8);
            *(ushort4*)(d + 12) = *(const ushort4*)(src + 12);
        }
        __syncthreads();
        short8 a = *reinterpret_cast<const short8*>(As + (wm * 16 + lr) * 32 + lq * 8);
        for (int ni = 0; ni < 4; ni++) {
            short8 bb = *reinterpret_cast<const short8*>(Bs + (wn * 64 + ni * 16 + lr) * 32 + lq * 8);
            acc[ni] = __builtin_amdgcn_mfma_f32_16x16x32_bf16(a, bb, acc[ni], 0, 0, 0);
        }
    }
    for (int ni = 0; ni < 4; ni++) {
        int cidx = wn * 64 + ni * 16 + lr;
        if (cidx >= NCLS) continue;
        float bg = b_gen[cidx];
        int mbase = mb * 32 + wm * 16 + lq * 4;
        for (int r = 0; r < 4; r++) {
            int mm = mbase + r;
            int s = mm >> 9;
            int bb_ = mm & 511;
            float v = (cidx == 3) ? -10000.f : (acc[ni][r] + bg);
            out[(size_t)bb_ * (NSTEP * NCLS) + s * NCLS + cidx] = v;
        }
    }
}

extern "C" void kernel_launch(void* const* d_in, const int* in_sizes, int n_in,
                              void* d_out, int out_size, void* d_ws, size_t ws_size,
                              hipStream_t stream) {
    const float* batch_H = (const float*)d_in[0];
    const int* text = (const int*)d_in[1];
    const float* W_i2h = (const float*)d_in[3];
    const float* W_h2h = (const float*)d_in[4];
    const float* b_h2h = (const float*)d_in[5];
    const float* W_score = (const float*)d_in[6];
    const float* W_ih = (const float*)d_in[7];
    const float* W_hh = (const float*)d_in[8];
    const float* b_ih = (const float*)d_in[9];
    const float* b_hh = (const float*)d_in[10];
    const float* W_gen = (const float*)d_in[11];
    const float* b_gen = (const float*)d_in[12];
    float* out = (float*)d_out;

    char* ws = (char*)d_ws;
    size_t off = 0;
    auto alloc = [&](size_t bytes) {
        void* p = ws + off;
        off += (bytes + 255) & ~(size_t)255;
        return p;
    };
    char* projF8 = (char*)alloc((size_t)16777216);    // [b][h][t] int8
    char* bHf8T = (char*)alloc((size_t)16777216);     // [b][i][t] int8 (transposed)
    char* Wh2h_q8 = (char*)alloc(65536);
    u16* Wi2h_bf = (u16*)alloc(65536 * 2);
    u16* Wcat3 = (u16*)alloc((size_t)524288 * 2);     // frag-swizzled LSTM weights
    float* bsum = (float*)alloc(1024 * 4);
    u16* WgenP = (u16*)alloc(32768 * 2);
    float* WohT = (float*)alloc((size_t)102400 * 4);  // [100][1024]
    u16* XcatS = (u16*)alloc((size_t)262144 * 2);     // A-frag-swizzled LSTM input
    u16* hbf_all = (u16*)alloc((size_t)NSTEP * NB * NH * 2);
    char* h8 = (char*)alloc((size_t)NB * NH);
    float* c_st = (float*)alloc((size_t)NB * NH * 4);

    prep_all<<<256, 256, 0, stream>>>(W_h2h, W_i2h, W_ih, W_hh, b_ih, b_hh, W_gen,
                                      Wh2h_q8, Wi2h_bf, Wcat3, bsum, WgenP, WohT, XcatS);
    gemm_projH5<<<512, 512, 0, stream>>>(batch_H, Wi2h_bf, projF8, bHf8T);
    for (int s = 0; s < NSTEP; s++) {
        attn_step8<<<512, 512, 0, stream>>>(h8, Wh2h_q8, b_h2h, W_score,
                                            projF8, bHf8T, XcatS, s);
        lstm_step7<<<512, 128, 0, stream>>>(XcatS, Wcat3, bsum, WohT, text, c_st,
                                            hbf_all, h8, XcatS, s);
    }
    gen_logits<<<416, 256, 0, stream>>>(hbf_all, WgenP, b_gen, out);
}